// Round 1
// baseline (402.534 us; speedup 1.0000x reference)
//
#include <hip/hip_runtime.h>
#include <math.h>

// Problem constants
#define NB   4
#define CCH  256
#define HH   64
#define WW   64
#define GG   8
#define GCH  32
#define PP   9
#define HIN  66
#define WIN  66
#define HWSZ 4096            // H*W
#define NPIX 16384           // N*H*W

// Workspace layout (floats)
#define XP_ELEMS  (NB*HIN*WIN*CCH)      // 4460544
#define X1_ELEMS  (NPIX*CCH)            // 4194304
#define OFF_ELEMS (NPIX*144)            // 2359296
#define MSK_ELEMS (NPIX*72)             // 1179648
#define AGG_ELEMS (NPIX*CCH)            // 4194304

// ---------------------------------------------------------------------------
// Kernel 1: input projection  x(NCHW) @ w_in -> xp (padded channels-last)
// block = 256 threads, tile 64 pixels (one h-row) x 64 out-channels
// ---------------------------------------------------------------------------
__global__ __launch_bounds__(256) void k_gemm_in(
    const float* __restrict__ x, const float* __restrict__ w_in,
    const float* __restrict__ b_in, float* __restrict__ xp)
{
    __shared__ float As[16 * 65];
    __shared__ float Ws[16 * 65];
    const int ct = blockIdx.x;       // 0..3 col tile
    const int h  = blockIdx.y;       // 0..63
    const int n  = blockIdx.z;       // 0..3
    const int tid = threadIdx.x;
    const int co0 = ct * 64;
    const int tr = tid >> 4, tc = tid & 15;

    const float* xa = x + (size_t)n * CCH * HWSZ + h * WW;  // + c*4096 + w

    float acc[4][4] = {};

    for (int k0 = 0; k0 < CCH; k0 += 16) {
#pragma unroll
        for (int l = 0; l < 4; l++) {
            int idx = tid + l * 256;
            int kk = idx >> 6, m = idx & 63;
            As[kk * 65 + m] = xa[(k0 + kk) * HWSZ + m];
            Ws[kk * 65 + m] = w_in[(k0 + kk) * CCH + co0 + m];
        }
        __syncthreads();
#pragma unroll
        for (int kk = 0; kk < 16; kk++) {
            float a[4], b[4];
#pragma unroll
            for (int i = 0; i < 4; i++) a[i] = As[kk * 65 + tr * 4 + i];
#pragma unroll
            for (int j = 0; j < 4; j++) b[j] = Ws[kk * 65 + tc * 4 + j];
#pragma unroll
            for (int i = 0; i < 4; i++)
#pragma unroll
                for (int j = 0; j < 4; j++) acc[i][j] += a[i] * b[j];
        }
        __syncthreads();
    }

    float bj[4];
#pragma unroll
    for (int j = 0; j < 4; j++) bj[j] = b_in[co0 + tc * 4 + j];

#pragma unroll
    for (int i = 0; i < 4; i++) {
        int w = tr * 4 + i;
        float4 v;
        v.x = acc[i][0] + bj[0];
        v.y = acc[i][1] + bj[1];
        v.z = acc[i][2] + bj[2];
        v.w = acc[i][3] + bj[3];
        // padded channels-last: xp[n][h+1][w+1][co]
        *(float4*)&xp[(((size_t)n * HIN + (h + 1)) * WIN + (w + 1)) * CCH + co0 + tc * 4] = v;
    }
}

// ---------------------------------------------------------------------------
// Kernel 2: depthwise 3x3 conv + bias + LayerNorm(C) + exact GELU -> x1
// block per (n, h, w-half of 32). LDS tile: 256 ch x 32 w (+1 pad)
// ---------------------------------------------------------------------------
__global__ __launch_bounds__(256) void k_dw_ln_gelu(
    const float* __restrict__ x, const float* __restrict__ w_dw,
    const float* __restrict__ b_dw, const float* __restrict__ ln_g,
    const float* __restrict__ ln_b, float* __restrict__ x1)
{
    __shared__ float sdw[CCH * 33];
    __shared__ float r1[8][32];
    __shared__ float r2[8][32];
    __shared__ float mu_s[32];
    __shared__ float rs_s[32];

    const int wh = blockIdx.x;   // 0..1
    const int h  = blockIdx.y;   // 0..63
    const int n  = blockIdx.z;   // 0..3
    const int tid = threadIdx.x;
    const int w0 = wh * 32;

    // Phase 1: depthwise conv into LDS
    {
        const int wl = tid & 31;
        const int csub = tid >> 5;   // 0..7
        for (int cb = 0; cb < CCH; cb += 8) {
            int c = cb + csub;
            const float* xc = x + ((size_t)n * CCH + c) * HWSZ;
            const float* wk = w_dw + c * 9;
            float acc = b_dw[c];
#pragma unroll
            for (int kh = 0; kh < 3; kh++) {
                int hy = h + kh - 1;
                if (hy < 0 || hy >= HH) continue;
#pragma unroll
                for (int kw = 0; kw < 3; kw++) {
                    int wx = w0 + wl + kw - 1;
                    if (wx < 0 || wx >= WW) continue;
                    acc += xc[hy * WW + wx] * wk[kh * 3 + kw];
                }
            }
            sdw[c * 33 + wl] = acc;
        }
    }
    __syncthreads();

    // Phase 2: per-pixel mean/var over 256 channels
    {
        const int wl = tid & 31;
        const int part = tid >> 5;   // 0..7
        float s1 = 0.f, s2 = 0.f;
        for (int q = 0; q < 32; q++) {
            float v = sdw[(part * 32 + q) * 33 + wl];
            s1 += v; s2 += v * v;
        }
        r1[part][wl] = s1;
        r2[part][wl] = s2;
    }
    __syncthreads();
    if (tid < 32) {
        float a1 = 0.f, a2 = 0.f;
#pragma unroll
        for (int q = 0; q < 8; q++) { a1 += r1[q][tid]; a2 += r2[q][tid]; }
        float mu = a1 * (1.0f / 256.0f);
        float var = a2 * (1.0f / 256.0f) - mu * mu;
        mu_s[tid] = mu;
        rs_s[tid] = rsqrtf(var + 1e-5f);
    }
    __syncthreads();

    // Phase 3: normalize + GELU, write channels-last
    {
        const int c = tid;
        const float ga = ln_g[c], be = ln_b[c];
        float* x1row = x1 + (((size_t)n * HH + h) * WW + w0) * CCH;
        for (int wl = 0; wl < 32; wl++) {
            float v = (sdw[c * 33 + wl] - mu_s[wl]) * rs_s[wl] * ga + be;
            float ge = 0.5f * v * (1.0f + erff(v * 0.70710678118654752f));
            x1row[wl * CCH + c] = ge;
        }
    }
}

// ---------------------------------------------------------------------------
// Kernel 3: x1 @ [w_off | w_mask] + bias -> off (16384x144), msk (16384x72)
// ---------------------------------------------------------------------------
__global__ __launch_bounds__(256) void k_gemm_offmask(
    const float* __restrict__ x1, const float* __restrict__ w_off,
    const float* __restrict__ b_off, const float* __restrict__ w_mask,
    const float* __restrict__ b_mask, float* __restrict__ off,
    float* __restrict__ msk)
{
    __shared__ float As[16 * 65];
    __shared__ float Ws[16 * 65];
    const int pt = blockIdx.x;   // 0..255
    const int ct = blockIdx.y;   // 0..3 (cols 0..215 valid)
    const int tid = threadIdx.x;
    const int p0 = pt * 64;
    const int co0 = ct * 64;
    const int tr = tid >> 4, tc = tid & 15;

    const float* Arow = x1 + (size_t)p0 * CCH;
    float acc[4][4] = {};

    for (int k0 = 0; k0 < CCH; k0 += 16) {
        {
            int m = tid >> 2, kq = tid & 3;
            float4 v = *(const float4*)&Arow[m * CCH + k0 + kq * 4];
            As[(kq * 4 + 0) * 65 + m] = v.x;
            As[(kq * 4 + 1) * 65 + m] = v.y;
            As[(kq * 4 + 2) * 65 + m] = v.z;
            As[(kq * 4 + 3) * 65 + m] = v.w;
        }
#pragma unroll
        for (int l = 0; l < 4; l++) {
            int idx = tid + l * 256;
            int kk = idx >> 6, nn = idx & 63;
            int col = co0 + nn;
            float wv = 0.f;
            if (col < 144) wv = w_off[(k0 + kk) * 144 + col];
            else if (col < 216) wv = w_mask[(k0 + kk) * 72 + col - 144];
            Ws[kk * 65 + nn] = wv;
        }
        __syncthreads();
#pragma unroll
        for (int kk = 0; kk < 16; kk++) {
            float a[4], b[4];
#pragma unroll
            for (int i = 0; i < 4; i++) a[i] = As[kk * 65 + tr * 4 + i];
#pragma unroll
            for (int j = 0; j < 4; j++) b[j] = Ws[kk * 65 + tc * 4 + j];
#pragma unroll
            for (int i = 0; i < 4; i++)
#pragma unroll
                for (int j = 0; j < 4; j++) acc[i][j] += a[i] * b[j];
        }
        __syncthreads();
    }

#pragma unroll
    for (int i = 0; i < 4; i++) {
        int p = p0 + tr * 4 + i;
#pragma unroll
        for (int j = 0; j < 4; j++) {
            int col = co0 + tc * 4 + j;
            float v = acc[i][j];
            if (col < 144)       off[(size_t)p * 144 + col] = v + b_off[col];
            else if (col < 216)  msk[(size_t)p * 72 + col - 144] = v + b_mask[col - 144];
        }
    }
}

// ---------------------------------------------------------------------------
// Kernel 4: deformable sampling + mask-softmax + aggregation -> agg (16384x256)
// one block per pixel; thread = (g = tid>>5, c = tid&31)
// sampling coords in padded image: fx = w + i + offx, fy = h + j + offy
// ---------------------------------------------------------------------------
__global__ __launch_bounds__(256) void k_sample_agg(
    const float* __restrict__ xp, const float* __restrict__ off,
    const float* __restrict__ msk, float* __restrict__ agg)
{
    const int s = blockIdx.x;            // 0..16383
    const int n = s >> 12;
    const int hw = s & 4095;
    const int h = hw >> 6, w = hw & 63;
    const int tid = threadIdx.x;
    const int g = tid >> 5, c = tid & 31;

    const float* offp = off + (size_t)s * 144 + g * 18;
    const float* mskp = msk + (size_t)s * 72 + g * 9;

    // softmax over 9 logits (redundant per lane; broadcast loads)
    float e[9];
    float mx = -1e30f;
#pragma unroll
    for (int p = 0; p < PP; p++) { e[p] = mskp[p]; mx = fmaxf(mx, e[p]); }
    float sum = 0.f;
#pragma unroll
    for (int p = 0; p < PP; p++) { e[p] = __expf(e[p] - mx); sum += e[p]; }
    const float rs = 1.0f / sum;

    const float* base = xp + (size_t)n * HIN * WIN * CCH + g * GCH + c;

    float acc = 0.f;
#pragma unroll
    for (int p = 0; p < PP; p++) {
        int i = p / 3, j = p % 3;   // i -> x offset, j -> y offset (kw-major DCNv3)
        float fx = (float)(w + i) + offp[p * 2 + 0];
        float fy = (float)(h + j) + offp[p * 2 + 1];
        float x0f = floorf(fx), y0f = floorf(fy);
        int x0 = (int)x0f, y0 = (int)y0f;
        float wx = fx - x0f, wy = fy - y0f;
        float m = e[p] * rs;

        float v00 = 0.f, v10 = 0.f, v01 = 0.f, v11 = 0.f;
        bool xv0 = (x0 >= 0) && (x0 < WIN);
        bool xv1 = (x0 + 1 >= 0) && (x0 + 1 < WIN);
        bool yv0 = (y0 >= 0) && (y0 < HIN);
        bool yv1 = (y0 + 1 >= 0) && (y0 + 1 < HIN);
        if (yv0) {
            const float* row = base + (size_t)y0 * WIN * CCH;
            if (xv0) v00 = row[(size_t)x0 * CCH];
            if (xv1) v10 = row[(size_t)(x0 + 1) * CCH];
        }
        if (yv1) {
            const float* row = base + (size_t)(y0 + 1) * WIN * CCH;
            if (xv0) v01 = row[(size_t)x0 * CCH];
            if (xv1) v11 = row[(size_t)(x0 + 1) * CCH];
        }
        float bil = v00 * (1.f - wx) * (1.f - wy) + v10 * wx * (1.f - wy)
                  + v01 * (1.f - wx) * wy         + v11 * wx * wy;
        acc += m * bil;
    }

    agg[(size_t)s * CCH + tid] = acc;
}

// ---------------------------------------------------------------------------
// Kernel 5: agg @ w_out + b_out -> BN -> SiLU -> out (NCHW)
// ---------------------------------------------------------------------------
__global__ __launch_bounds__(256) void k_gemm_out(
    const float* __restrict__ agg, const float* __restrict__ w_out,
    const float* __restrict__ b_out, const float* __restrict__ bn_g,
    const float* __restrict__ bn_b, const float* __restrict__ bn_mean,
    const float* __restrict__ bn_var, float* __restrict__ out)
{
    __shared__ float As[16 * 65];
    __shared__ float Ws[16 * 65];
    const int pt = blockIdx.x;   // 0..255
    const int ct = blockIdx.y;   // 0..3
    const int tid = threadIdx.x;
    const int p0 = pt * 64;
    const int co0 = ct * 64;
    const int tr = tid >> 4, tc = tid & 15;

    const float* Arow = agg + (size_t)p0 * CCH;
    float acc[4][4] = {};

    for (int k0 = 0; k0 < CCH; k0 += 16) {
        {
            int m = tid >> 2, kq = tid & 3;
            float4 v = *(const float4*)&Arow[m * CCH + k0 + kq * 4];
            As[(kq * 4 + 0) * 65 + m] = v.x;
            As[(kq * 4 + 1) * 65 + m] = v.y;
            As[(kq * 4 + 2) * 65 + m] = v.z;
            As[(kq * 4 + 3) * 65 + m] = v.w;
        }
#pragma unroll
        for (int l = 0; l < 4; l++) {
            int idx = tid + l * 256;
            int kk = idx >> 6, nn = idx & 63;
            Ws[kk * 65 + nn] = w_out[(k0 + kk) * CCH + co0 + nn];
        }
        __syncthreads();
#pragma unroll
        for (int kk = 0; kk < 16; kk++) {
            float a[4], b[4];
#pragma unroll
            for (int i = 0; i < 4; i++) a[i] = As[kk * 65 + tr * 4 + i];
#pragma unroll
            for (int j = 0; j < 4; j++) b[j] = Ws[kk * 65 + tc * 4 + j];
#pragma unroll
            for (int i = 0; i < 4; i++)
#pragma unroll
                for (int j = 0; j < 4; j++) acc[i][j] += a[i] * b[j];
        }
        __syncthreads();
    }

    const int n = p0 >> 12;
    const int hw0 = p0 & 4095;
#pragma unroll
    for (int j = 0; j < 4; j++) {
        int co = co0 + tc * 4 + j;
        float mean = bn_mean[co];
        float rstd = rsqrtf(bn_var[co] + 1e-5f);
        float gg = bn_g[co], bb = bn_b[co], bo = b_out[co];
        float tmp[4];
#pragma unroll
        for (int i = 0; i < 4; i++) {
            float y = acc[i][j] + bo;
            float yh = (y - mean) * rstd * gg + bb;
            tmp[i] = yh / (1.0f + __expf(-yh));   // SiLU
        }
        float4 v = make_float4(tmp[0], tmp[1], tmp[2], tmp[3]);
        *(float4*)&out[((size_t)n * CCH + co) * HWSZ + hw0 + tr * 4] = v;
    }
}

// ---------------------------------------------------------------------------
extern "C" void kernel_launch(void* const* d_in, const int* in_sizes, int n_in,
                              void* d_out, int out_size, void* d_ws, size_t ws_size,
                              hipStream_t stream)
{
    const float* x       = (const float*)d_in[0];
    const float* w_in    = (const float*)d_in[1];
    const float* b_in    = (const float*)d_in[2];
    const float* w_dw    = (const float*)d_in[3];
    const float* b_dw    = (const float*)d_in[4];
    const float* ln_g    = (const float*)d_in[5];
    const float* ln_b    = (const float*)d_in[6];
    const float* w_off   = (const float*)d_in[7];
    const float* b_off   = (const float*)d_in[8];
    const float* w_mask  = (const float*)d_in[9];
    const float* b_mask  = (const float*)d_in[10];
    const float* w_out   = (const float*)d_in[11];
    const float* b_out   = (const float*)d_in[12];
    const float* bn_g    = (const float*)d_in[13];
    const float* bn_b    = (const float*)d_in[14];
    const float* bn_mean = (const float*)d_in[15];
    const float* bn_var  = (const float*)d_in[16];
    float* out = (float*)d_out;

    float* ws  = (float*)d_ws;
    float* xp  = ws;                       // padded channels-last x_proj
    float* x1  = xp + XP_ELEMS;
    float* off = x1 + X1_ELEMS;
    float* msk = off + OFF_ELEMS;
    float* agg = msk + MSK_ELEMS;
    // total: 16,388,096 floats = ~65.6 MB of workspace

    // zero the padded buffer (pad ring must be 0; interior overwritten)
    hipMemsetAsync(xp, 0, (size_t)XP_ELEMS * sizeof(float), stream);

    k_gemm_in<<<dim3(4, 64, 4), 256, 0, stream>>>(x, w_in, b_in, xp);
    k_dw_ln_gelu<<<dim3(2, 64, 4), 256, 0, stream>>>(x, w_dw, b_dw, ln_g, ln_b, x1);
    k_gemm_offmask<<<dim3(256, 4), 256, 0, stream>>>(x1, w_off, b_off, w_mask, b_mask, off, msk);
    k_sample_agg<<<dim3(16384), 256, 0, stream>>>(xp, off, msk, agg);
    k_gemm_out<<<dim3(256, 4), 256, 0, stream>>>(agg, w_out, b_out, bn_g, bn_b, bn_mean, bn_var, out);
}

// Round 2
// 331.109 us; speedup vs baseline: 1.2157x; 1.2157x over previous
//
#include <hip/hip_runtime.h>
#include <math.h>

// Problem constants
#define NB   4
#define CCH  256
#define HH   64
#define WW   64
#define GG   8
#define GCH  32
#define PP   9
#define HIN  66
#define WIN  66
#define HWSZ 4096            // H*W
#define NPIX 16384           // N*H*W

// Workspace layout (floats)
#define XP_ELEMS  (NB*HIN*WIN*CCH)      // 4460544
#define X1_ELEMS  (NPIX*CCH)            // 4194304
#define OFF_ELEMS (NPIX*144)            // 2359296
#define MSK_ELEMS (NPIX*72)             // 1179648
#define AGG_ELEMS (NPIX*CCH)            // 4194304

typedef __attribute__((ext_vector_type(8))) short bf16x8;
typedef __attribute__((ext_vector_type(4))) float f32x4;

__device__ __forceinline__ unsigned short f2bf(float f) {
    unsigned int u = __float_as_uint(f);
    unsigned int r = (u + 0x7FFFu + ((u >> 16) & 1u)) >> 16;
    return (unsigned short)r;
}

// LDS tile strides (bf16 elems): row = 32 k + 8 pad
#define AK 40
// As: 128 rows x 40 -> 10240 B ; Ws: 64 rows x 40 -> 5120 B

// ---------------------------------------------------------------------------
// Kernel 0: zero only the pad ring of xp (interior overwritten by k_gemm_in)
// grid = 1040 blocks (260 ring pixels x 4 n), 64 threads -> one float4 each
// ---------------------------------------------------------------------------
__global__ __launch_bounds__(64) void k_zero_ring(float* __restrict__ xp)
{
    int b = blockIdx.x;
    int n = b / 260;
    int rp = b % 260;
    int h, w;
    if (rp < 66)       { h = 0;        w = rp; }
    else if (rp < 132) { h = 65;       w = rp - 66; }
    else if (rp < 196) { h = rp - 131; w = 0; }    // h = 1..64
    else               { h = rp - 195; w = 65; }   // h = 1..64
    float4 z = make_float4(0.f, 0.f, 0.f, 0.f);
    *(float4*)&xp[(((size_t)n * HIN + h) * WIN + w) * CCH + threadIdx.x * 4] = z;
}

// ---------------------------------------------------------------------------
// Kernel 1: input projection  x(NCHW) @ w_in -> xp (padded channels-last)
// MFMA bf16: block tile 128(m) x 64(n), BK=32, 4 waves x (2 mt x 4 nt)
// A[m][k] = x[n][k][hw0+m]  (m contiguous in global)
// ---------------------------------------------------------------------------
__global__ __launch_bounds__(256) void k_gemm_in(
    const float* __restrict__ x, const float* __restrict__ w_in,
    const float* __restrict__ b_in, float* __restrict__ xp)
{
    __shared__ short As[128 * AK];
    __shared__ short Ws[64 * AK];

    const int m0  = blockIdx.x * 128;       // pixel base (within one n: 4096/128=32)
    const int co0 = blockIdx.y * 64;
    const int tid = threadIdx.x;
    const int n   = m0 >> 12;
    const int hw0 = m0 & 4095;

    const int wave = tid >> 6;
    const int lane = tid & 63;
    const int r16  = lane & 15;
    const int quad = lane >> 4;
    const int mw   = wave * 32;

    const float* xa = x + (size_t)n * CCH * HWSZ + hw0;

    f32x4 acc[2][4];
#pragma unroll
    for (int i = 0; i < 2; i++)
#pragma unroll
        for (int j = 0; j < 4; j++) acc[i][j] = (f32x4){0.f, 0.f, 0.f, 0.f};

    for (int k0 = 0; k0 < CCH; k0 += 32) {
        // stage A: 128x32, coalesced along m
#pragma unroll
        for (int l = 0; l < 16; l++) {
            int idx = tid + l * 256;
            int kk = idx >> 7, m = idx & 127;
            As[m * AK + kk] = (short)f2bf(xa[(size_t)(k0 + kk) * HWSZ + m]);
        }
        // stage W: 32x64 -> Ws[n][k]
#pragma unroll
        for (int l = 0; l < 8; l++) {
            int idx = tid + l * 256;
            int nn = idx & 63, kk = idx >> 6;
            Ws[nn * AK + kk] = (short)f2bf(w_in[(size_t)(k0 + kk) * CCH + co0 + nn]);
        }
        __syncthreads();

        bf16x8 a0 = *(const bf16x8*)&As[(mw + r16) * AK + quad * 8];
        bf16x8 a1 = *(const bf16x8*)&As[(mw + 16 + r16) * AK + quad * 8];
#pragma unroll
        for (int nt = 0; nt < 4; nt++) {
            bf16x8 bfr = *(const bf16x8*)&Ws[(nt * 16 + r16) * AK + quad * 8];
            acc[0][nt] = __builtin_amdgcn_mfma_f32_16x16x32_bf16(a0, bfr, acc[0][nt], 0, 0, 0);
            acc[1][nt] = __builtin_amdgcn_mfma_f32_16x16x32_bf16(a1, bfr, acc[1][nt], 0, 0, 0);
        }
        __syncthreads();
    }

    // epilogue: C col = co0+nt*16+r16, rows = mw+mt*16+quad*4+r
#pragma unroll
    for (int nt = 0; nt < 4; nt++) {
        int co = co0 + nt * 16 + r16;
        float bias = b_in[co];
#pragma unroll
        for (int mt = 0; mt < 2; mt++) {
            int mbase = mw + mt * 16 + quad * 4;
#pragma unroll
            for (int r = 0; r < 4; r++) {
                int hw = hw0 + mbase + r;
                int h = hw >> 6, w = hw & 63;
                xp[(((size_t)n * HIN + (h + 1)) * WIN + (w + 1)) * CCH + co] =
                    acc[mt][nt][r] + bias;
            }
        }
    }
}

// ---------------------------------------------------------------------------
// Kernel 2: depthwise 3x3 conv + bias + LayerNorm(C) + exact GELU -> x1
// ---------------------------------------------------------------------------
__global__ __launch_bounds__(256) void k_dw_ln_gelu(
    const float* __restrict__ x, const float* __restrict__ w_dw,
    const float* __restrict__ b_dw, const float* __restrict__ ln_g,
    const float* __restrict__ ln_b, float* __restrict__ x1)
{
    __shared__ float sdw[CCH * 33];
    __shared__ float r1[8][32];
    __shared__ float r2[8][32];
    __shared__ float mu_s[32];
    __shared__ float rs_s[32];

    const int wh = blockIdx.x;
    const int h  = blockIdx.y;
    const int n  = blockIdx.z;
    const int tid = threadIdx.x;
    const int w0 = wh * 32;

    {
        const int wl = tid & 31;
        const int csub = tid >> 5;
        for (int cb = 0; cb < CCH; cb += 8) {
            int c = cb + csub;
            const float* xc = x + ((size_t)n * CCH + c) * HWSZ;
            const float* wk = w_dw + c * 9;
            float acc = b_dw[c];
#pragma unroll
            for (int kh = 0; kh < 3; kh++) {
                int hy = h + kh - 1;
                if (hy < 0 || hy >= HH) continue;
#pragma unroll
                for (int kw = 0; kw < 3; kw++) {
                    int wx = w0 + wl + kw - 1;
                    if (wx < 0 || wx >= WW) continue;
                    acc += xc[hy * WW + wx] * wk[kh * 3 + kw];
                }
            }
            sdw[c * 33 + wl] = acc;
        }
    }
    __syncthreads();

    {
        const int wl = tid & 31;
        const int part = tid >> 5;
        float s1 = 0.f, s2 = 0.f;
        for (int q = 0; q < 32; q++) {
            float v = sdw[(part * 32 + q) * 33 + wl];
            s1 += v; s2 += v * v;
        }
        r1[part][wl] = s1;
        r2[part][wl] = s2;
    }
    __syncthreads();
    if (tid < 32) {
        float a1 = 0.f, a2 = 0.f;
#pragma unroll
        for (int q = 0; q < 8; q++) { a1 += r1[q][tid]; a2 += r2[q][tid]; }
        float mu = a1 * (1.0f / 256.0f);
        float var = a2 * (1.0f / 256.0f) - mu * mu;
        mu_s[tid] = mu;
        rs_s[tid] = rsqrtf(var + 1e-5f);
    }
    __syncthreads();

    {
        const int c = tid;
        const float ga = ln_g[c], be = ln_b[c];
        float* x1row = x1 + (((size_t)n * HH + h) * WW + w0) * CCH;
        for (int wl = 0; wl < 32; wl++) {
            float v = (sdw[c * 33 + wl] - mu_s[wl]) * rs_s[wl] * ga + be;
            float ge = 0.5f * v * (1.0f + erff(v * 0.70710678118654752f));
            x1row[wl * CCH + c] = ge;
        }
    }
}

// ---------------------------------------------------------------------------
// Kernel 3: x1 @ [w_off | w_mask] + bias -> off (16384x144), msk (16384x72)
// MFMA bf16, A row-major k-contiguous
// ---------------------------------------------------------------------------
__global__ __launch_bounds__(256) void k_gemm_offmask(
    const float* __restrict__ x1, const float* __restrict__ w_off,
    const float* __restrict__ b_off, const float* __restrict__ w_mask,
    const float* __restrict__ b_mask, float* __restrict__ off,
    float* __restrict__ msk)
{
    __shared__ short As[128 * AK];
    __shared__ short Ws[64 * AK];

    const int m0  = blockIdx.x * 128;
    const int co0 = blockIdx.y * 64;       // cols 0..215 valid
    const int tid = threadIdx.x;

    const int wave = tid >> 6;
    const int lane = tid & 63;
    const int r16  = lane & 15;
    const int quad = lane >> 4;
    const int mw   = wave * 32;

    f32x4 acc[2][4];
#pragma unroll
    for (int i = 0; i < 2; i++)
#pragma unroll
        for (int j = 0; j < 4; j++) acc[i][j] = (f32x4){0.f, 0.f, 0.f, 0.f};

    for (int k0 = 0; k0 < CCH; k0 += 32) {
        // stage A via float4 along k
#pragma unroll
        for (int l = 0; l < 4; l++) {
            int idx = tid + l * 256;
            int m = idx >> 3, kq = idx & 7;
            float4 v = *(const float4*)&x1[(size_t)(m0 + m) * CCH + k0 + kq * 4];
            short4 s;
            s.x = (short)f2bf(v.x); s.y = (short)f2bf(v.y);
            s.z = (short)f2bf(v.z); s.w = (short)f2bf(v.w);
            *(short4*)&As[m * AK + kq * 4] = s;
        }
        // stage W (concat of w_off | w_mask)
#pragma unroll
        for (int l = 0; l < 8; l++) {
            int idx = tid + l * 256;
            int nn = idx & 63, kk = idx >> 6;
            int col = co0 + nn;
            float wv = 0.f;
            if (col < 144)      wv = w_off[(size_t)(k0 + kk) * 144 + col];
            else if (col < 216) wv = w_mask[(size_t)(k0 + kk) * 72 + col - 144];
            Ws[nn * AK + kk] = (short)f2bf(wv);
        }
        __syncthreads();

        bf16x8 a0 = *(const bf16x8*)&As[(mw + r16) * AK + quad * 8];
        bf16x8 a1 = *(const bf16x8*)&As[(mw + 16 + r16) * AK + quad * 8];
#pragma unroll
        for (int nt = 0; nt < 4; nt++) {
            bf16x8 bfr = *(const bf16x8*)&Ws[(nt * 16 + r16) * AK + quad * 8];
            acc[0][nt] = __builtin_amdgcn_mfma_f32_16x16x32_bf16(a0, bfr, acc[0][nt], 0, 0, 0);
            acc[1][nt] = __builtin_amdgcn_mfma_f32_16x16x32_bf16(a1, bfr, acc[1][nt], 0, 0, 0);
        }
        __syncthreads();
    }

#pragma unroll
    for (int nt = 0; nt < 4; nt++) {
        int col = co0 + nt * 16 + r16;
        if (col >= 216) continue;
        float bias = (col < 144) ? b_off[col] : b_mask[col - 144];
#pragma unroll
        for (int mt = 0; mt < 2; mt++) {
            int mbase = m0 + mw + mt * 16 + quad * 4;
#pragma unroll
            for (int r = 0; r < 4; r++) {
                int p = mbase + r;
                float v = acc[mt][nt][r] + bias;
                if (col < 144) off[(size_t)p * 144 + col] = v;
                else           msk[(size_t)p * 72 + col - 144] = v;
            }
        }
    }
}

// ---------------------------------------------------------------------------
// Kernel 4: deformable sampling + mask-softmax + aggregation -> agg (16384x256)
// ---------------------------------------------------------------------------
__global__ __launch_bounds__(256) void k_sample_agg(
    const float* __restrict__ xp, const float* __restrict__ off,
    const float* __restrict__ msk, float* __restrict__ agg)
{
    const int s = blockIdx.x;
    const int n = s >> 12;
    const int hw = s & 4095;
    const int h = hw >> 6, w = hw & 63;
    const int tid = threadIdx.x;
    const int g = tid >> 5, c = tid & 31;

    const float* offp = off + (size_t)s * 144 + g * 18;
    const float* mskp = msk + (size_t)s * 72 + g * 9;

    float e[9];
    float mx = -1e30f;
#pragma unroll
    for (int p = 0; p < PP; p++) { e[p] = mskp[p]; mx = fmaxf(mx, e[p]); }
    float sum = 0.f;
#pragma unroll
    for (int p = 0; p < PP; p++) { e[p] = __expf(e[p] - mx); sum += e[p]; }
    const float rs = 1.0f / sum;

    const float* base = xp + (size_t)n * HIN * WIN * CCH + g * GCH + c;

    float acc = 0.f;
#pragma unroll
    for (int p = 0; p < PP; p++) {
        int i = p / 3, j = p % 3;
        float fx = (float)(w + i) + offp[p * 2 + 0];
        float fy = (float)(h + j) + offp[p * 2 + 1];
        float x0f = floorf(fx), y0f = floorf(fy);
        int x0 = (int)x0f, y0 = (int)y0f;
        float wx = fx - x0f, wy = fy - y0f;
        float m = e[p] * rs;

        float v00 = 0.f, v10 = 0.f, v01 = 0.f, v11 = 0.f;
        bool xv0 = (x0 >= 0) && (x0 < WIN);
        bool xv1 = (x0 + 1 >= 0) && (x0 + 1 < WIN);
        bool yv0 = (y0 >= 0) && (y0 < HIN);
        bool yv1 = (y0 + 1 >= 0) && (y0 + 1 < HIN);
        if (yv0) {
            const float* row = base + (size_t)y0 * WIN * CCH;
            if (xv0) v00 = row[(size_t)x0 * CCH];
            if (xv1) v10 = row[(size_t)(x0 + 1) * CCH];
        }
        if (yv1) {
            const float* row = base + (size_t)(y0 + 1) * WIN * CCH;
            if (xv0) v01 = row[(size_t)x0 * CCH];
            if (xv1) v11 = row[(size_t)(x0 + 1) * CCH];
        }
        float bil = v00 * (1.f - wx) * (1.f - wy) + v10 * wx * (1.f - wy)
                  + v01 * (1.f - wx) * wy         + v11 * wx * wy;
        acc += m * bil;
    }

    agg[(size_t)s * CCH + tid] = acc;
}

// ---------------------------------------------------------------------------
// Kernel 5: agg @ w_out + b_out -> BN -> SiLU -> out (NCHW), MFMA bf16
// C-layout gives each lane 4 consecutive pixels per col -> float4 NCHW stores
// ---------------------------------------------------------------------------
__global__ __launch_bounds__(256) void k_gemm_out(
    const float* __restrict__ agg, const float* __restrict__ w_out,
    const float* __restrict__ b_out, const float* __restrict__ bn_g,
    const float* __restrict__ bn_b, const float* __restrict__ bn_mean,
    const float* __restrict__ bn_var, float* __restrict__ out)
{
    __shared__ short As[128 * AK];
    __shared__ short Ws[64 * AK];

    const int m0  = blockIdx.x * 128;
    const int co0 = blockIdx.y * 64;
    const int tid = threadIdx.x;
    const int n   = m0 >> 12;
    const int hw0 = m0 & 4095;

    const int wave = tid >> 6;
    const int lane = tid & 63;
    const int r16  = lane & 15;
    const int quad = lane >> 4;
    const int mw   = wave * 32;

    f32x4 acc[2][4];
#pragma unroll
    for (int i = 0; i < 2; i++)
#pragma unroll
        for (int j = 0; j < 4; j++) acc[i][j] = (f32x4){0.f, 0.f, 0.f, 0.f};

    for (int k0 = 0; k0 < CCH; k0 += 32) {
#pragma unroll
        for (int l = 0; l < 4; l++) {
            int idx = tid + l * 256;
            int m = idx >> 3, kq = idx & 7;
            float4 v = *(const float4*)&agg[(size_t)(m0 + m) * CCH + k0 + kq * 4];
            short4 s;
            s.x = (short)f2bf(v.x); s.y = (short)f2bf(v.y);
            s.z = (short)f2bf(v.z); s.w = (short)f2bf(v.w);
            *(short4*)&As[m * AK + kq * 4] = s;
        }
#pragma unroll
        for (int l = 0; l < 8; l++) {
            int idx = tid + l * 256;
            int nn = idx & 63, kk = idx >> 6;
            Ws[nn * AK + kk] = (short)f2bf(w_out[(size_t)(k0 + kk) * CCH + co0 + nn]);
        }
        __syncthreads();

        bf16x8 a0 = *(const bf16x8*)&As[(mw + r16) * AK + quad * 8];
        bf16x8 a1 = *(const bf16x8*)&As[(mw + 16 + r16) * AK + quad * 8];
#pragma unroll
        for (int nt = 0; nt < 4; nt++) {
            bf16x8 bfr = *(const bf16x8*)&Ws[(nt * 16 + r16) * AK + quad * 8];
            acc[0][nt] = __builtin_amdgcn_mfma_f32_16x16x32_bf16(a0, bfr, acc[0][nt], 0, 0, 0);
            acc[1][nt] = __builtin_amdgcn_mfma_f32_16x16x32_bf16(a1, bfr, acc[1][nt], 0, 0, 0);
        }
        __syncthreads();
    }

#pragma unroll
    for (int nt = 0; nt < 4; nt++) {
        int co = co0 + nt * 16 + r16;
        float mean = bn_mean[co];
        float rstd = rsqrtf(bn_var[co] + 1e-5f);
        float gg = bn_g[co], bb = bn_b[co], bo = b_out[co];
#pragma unroll
        for (int mt = 0; mt < 2; mt++) {
            int hwb = hw0 + mw + mt * 16 + quad * 4;
            float tmp[4];
#pragma unroll
            for (int r = 0; r < 4; r++) {
                float y = acc[mt][nt][r] + bo;
                float yh = (y - mean) * rstd * gg + bb;
                tmp[r] = yh / (1.0f + __expf(-yh));
            }
            float4 v = make_float4(tmp[0], tmp[1], tmp[2], tmp[3]);
            *(float4*)&out[((size_t)n * CCH + co) * HWSZ + hwb] = v;
        }
    }
}

// ---------------------------------------------------------------------------
extern "C" void kernel_launch(void* const* d_in, const int* in_sizes, int n_in,
                              void* d_out, int out_size, void* d_ws, size_t ws_size,
                              hipStream_t stream)
{
    const float* x       = (const float*)d_in[0];
    const float* w_in    = (const float*)d_in[1];
    const float* b_in    = (const float*)d_in[2];
    const float* w_dw    = (const float*)d_in[3];
    const float* b_dw    = (const float*)d_in[4];
    const float* ln_g    = (const float*)d_in[5];
    const float* ln_b    = (const float*)d_in[6];
    const float* w_off   = (const float*)d_in[7];
    const float* b_off   = (const float*)d_in[8];
    const float* w_mask  = (const float*)d_in[9];
    const float* b_mask  = (const float*)d_in[10];
    const float* w_out   = (const float*)d_in[11];
    const float* b_out   = (const float*)d_in[12];
    const float* bn_g    = (const float*)d_in[13];
    const float* bn_b    = (const float*)d_in[14];
    const float* bn_mean = (const float*)d_in[15];
    const float* bn_var  = (const float*)d_in[16];
    float* out = (float*)d_out;

    float* ws  = (float*)d_ws;
    float* xp  = ws;
    float* x1  = xp + XP_ELEMS;
    float* off = x1 + X1_ELEMS;
    float* msk = off + OFF_ELEMS;
    float* agg = msk + MSK_ELEMS;

    k_zero_ring<<<dim3(1040), 64, 0, stream>>>(xp);
    k_gemm_in<<<dim3(128, 4), 256, 0, stream>>>(x, w_in, b_in, xp);
    k_dw_ln_gelu<<<dim3(2, 64, 4), 256, 0, stream>>>(x, w_dw, b_dw, ln_g, ln_b, x1);
    k_gemm_offmask<<<dim3(128, 4), 256, 0, stream>>>(x1, w_off, b_off, w_mask, b_mask, off, msk);
    k_sample_agg<<<dim3(16384), 256, 0, stream>>>(xp, off, msk, agg);
    k_gemm_out<<<dim3(128, 4), 256, 0, stream>>>(agg, w_out, b_out, bn_g, bn_b, bn_mean, bn_var, out);
}

// Round 3
// 269.343 us; speedup vs baseline: 1.4945x; 1.2293x over previous
//
#include <hip/hip_runtime.h>
#include <math.h>

// Problem constants
#define NB   4
#define CCH  256
#define HH   64
#define WW   64
#define GG   8
#define GCH  32
#define PP   9
#define HIN  66
#define WIN  66
#define HWSZ 4096            // H*W
#define NPIX 16384           // N*H*W

// Workspace layout (floats)
#define XP_ELEMS  (NB*HIN*WIN*CCH)      // 4460544
#define X1_ELEMS  (NPIX*CCH)            // 4194304
#define OFF_ELEMS (NPIX*144)            // 2359296
#define MSK_ELEMS (NPIX*72)             // 1179648
#define AGG_ELEMS (NPIX*CCH)            // 4194304

typedef __attribute__((ext_vector_type(8))) short bf16x8;
typedef __attribute__((ext_vector_type(4))) float f32x4;

__device__ __forceinline__ unsigned short f2bf(float f) {
    unsigned int u = __float_as_uint(f);
    unsigned int r = (u + 0x7FFFu + ((u >> 16) & 1u)) >> 16;
    return (unsigned short)r;
}

// LDS tile strides (bf16 elems): row = 32 k + 8 pad
#define AK 40

// ---------------------------------------------------------------------------
// Kernel 0: zero only the pad ring of xp (interior overwritten by k_gemm_in)
// ---------------------------------------------------------------------------
__global__ __launch_bounds__(64) void k_zero_ring(float* __restrict__ xp)
{
    int b = blockIdx.x;
    int n = b / 260;
    int rp = b % 260;
    int h, w;
    if (rp < 66)       { h = 0;        w = rp; }
    else if (rp < 132) { h = 65;       w = rp - 66; }
    else if (rp < 196) { h = rp - 131; w = 0; }    // h = 1..64
    else               { h = rp - 195; w = 65; }   // h = 1..64
    float4 z = make_float4(0.f, 0.f, 0.f, 0.f);
    *(float4*)&xp[(((size_t)n * HIN + h) * WIN + w) * CCH + threadIdx.x * 4] = z;
}

// ---------------------------------------------------------------------------
// Kernel 1: input projection  x(NCHW) @ w_in -> xp (padded channels-last)
// MFMA bf16: block tile 128(m) x 64(n), BK=32, 4 waves x (2 mt x 4 nt)
// ---------------------------------------------------------------------------
__global__ __launch_bounds__(256) void k_gemm_in(
    const float* __restrict__ x, const float* __restrict__ w_in,
    const float* __restrict__ b_in, float* __restrict__ xp)
{
    __shared__ short As[128 * AK];
    __shared__ short Ws[64 * AK];

    const int m0  = blockIdx.x * 128;
    const int co0 = blockIdx.y * 64;
    const int tid = threadIdx.x;
    const int n   = m0 >> 12;
    const int hw0 = m0 & 4095;

    const int wave = tid >> 6;
    const int lane = tid & 63;
    const int r16  = lane & 15;
    const int quad = lane >> 4;
    const int mw   = wave * 32;

    const float* xa = x + (size_t)n * CCH * HWSZ + hw0;

    f32x4 acc[2][4];
#pragma unroll
    for (int i = 0; i < 2; i++)
#pragma unroll
        for (int j = 0; j < 4; j++) acc[i][j] = (f32x4){0.f, 0.f, 0.f, 0.f};

    for (int k0 = 0; k0 < CCH; k0 += 32) {
#pragma unroll
        for (int l = 0; l < 16; l++) {
            int idx = tid + l * 256;
            int kk = idx >> 7, m = idx & 127;
            As[m * AK + kk] = (short)f2bf(xa[(size_t)(k0 + kk) * HWSZ + m]);
        }
#pragma unroll
        for (int l = 0; l < 8; l++) {
            int idx = tid + l * 256;
            int nn = idx & 63, kk = idx >> 6;
            Ws[nn * AK + kk] = (short)f2bf(w_in[(size_t)(k0 + kk) * CCH + co0 + nn]);
        }
        __syncthreads();

        bf16x8 a0 = *(const bf16x8*)&As[(mw + r16) * AK + quad * 8];
        bf16x8 a1 = *(const bf16x8*)&As[(mw + 16 + r16) * AK + quad * 8];
#pragma unroll
        for (int nt = 0; nt < 4; nt++) {
            bf16x8 bfr = *(const bf16x8*)&Ws[(nt * 16 + r16) * AK + quad * 8];
            acc[0][nt] = __builtin_amdgcn_mfma_f32_16x16x32_bf16(a0, bfr, acc[0][nt], 0, 0, 0);
            acc[1][nt] = __builtin_amdgcn_mfma_f32_16x16x32_bf16(a1, bfr, acc[1][nt], 0, 0, 0);
        }
        __syncthreads();
    }

#pragma unroll
    for (int nt = 0; nt < 4; nt++) {
        int co = co0 + nt * 16 + r16;
        float bias = b_in[co];
#pragma unroll
        for (int mt = 0; mt < 2; mt++) {
            int mbase = mw + mt * 16 + quad * 4;
#pragma unroll
            for (int r = 0; r < 4; r++) {
                int hw = hw0 + mbase + r;
                int h = hw >> 6, w = hw & 63;
                xp[(((size_t)n * HIN + (h + 1)) * WIN + (w + 1)) * CCH + co] =
                    acc[mt][nt][r] + bias;
            }
        }
    }
}

// ---------------------------------------------------------------------------
// Kernel 2: depthwise 3x3 conv + bias + LayerNorm(C) + exact GELU -> x1
// ---------------------------------------------------------------------------
__global__ __launch_bounds__(256) void k_dw_ln_gelu(
    const float* __restrict__ x, const float* __restrict__ w_dw,
    const float* __restrict__ b_dw, const float* __restrict__ ln_g,
    const float* __restrict__ ln_b, float* __restrict__ x1)
{
    __shared__ float sdw[CCH * 33];
    __shared__ float r1[8][32];
    __shared__ float r2[8][32];
    __shared__ float mu_s[32];
    __shared__ float rs_s[32];

    const int wh = blockIdx.x;
    const int h  = blockIdx.y;
    const int n  = blockIdx.z;
    const int tid = threadIdx.x;
    const int w0 = wh * 32;

    {
        const int wl = tid & 31;
        const int csub = tid >> 5;
        for (int cb = 0; cb < CCH; cb += 8) {
            int c = cb + csub;
            const float* xc = x + ((size_t)n * CCH + c) * HWSZ;
            const float* wk = w_dw + c * 9;
            float acc = b_dw[c];
#pragma unroll
            for (int kh = 0; kh < 3; kh++) {
                int hy = h + kh - 1;
                if (hy < 0 || hy >= HH) continue;
#pragma unroll
                for (int kw = 0; kw < 3; kw++) {
                    int wx = w0 + wl + kw - 1;
                    if (wx < 0 || wx >= WW) continue;
                    acc += xc[hy * WW + wx] * wk[kh * 3 + kw];
                }
            }
            sdw[c * 33 + wl] = acc;
        }
    }
    __syncthreads();

    {
        const int wl = tid & 31;
        const int part = tid >> 5;
        float s1 = 0.f, s2 = 0.f;
        for (int q = 0; q < 32; q++) {
            float v = sdw[(part * 32 + q) * 33 + wl];
            s1 += v; s2 += v * v;
        }
        r1[part][wl] = s1;
        r2[part][wl] = s2;
    }
    __syncthreads();
    if (tid < 32) {
        float a1 = 0.f, a2 = 0.f;
#pragma unroll
        for (int q = 0; q < 8; q++) { a1 += r1[q][tid]; a2 += r2[q][tid]; }
        float mu = a1 * (1.0f / 256.0f);
        float var = a2 * (1.0f / 256.0f) - mu * mu;
        mu_s[tid] = mu;
        rs_s[tid] = rsqrtf(var + 1e-5f);
    }
    __syncthreads();

    {
        const int c = tid;
        const float ga = ln_g[c], be = ln_b[c];
        float* x1row = x1 + (((size_t)n * HH + h) * WW + w0) * CCH;
        for (int wl = 0; wl < 32; wl++) {
            float v = (sdw[c * 33 + wl] - mu_s[wl]) * rs_s[wl] * ga + be;
            float ge = 0.5f * v * (1.0f + erff(v * 0.70710678118654752f));
            x1row[wl * CCH + c] = ge;
        }
    }
}

// ---------------------------------------------------------------------------
// Kernel 3: x1 @ [w_off | w_mask] + bias -> off (16384x144), msk (16384x72)
// ---------------------------------------------------------------------------
__global__ __launch_bounds__(256) void k_gemm_offmask(
    const float* __restrict__ x1, const float* __restrict__ w_off,
    const float* __restrict__ b_off, const float* __restrict__ w_mask,
    const float* __restrict__ b_mask, float* __restrict__ off,
    float* __restrict__ msk)
{
    __shared__ short As[128 * AK];
    __shared__ short Ws[64 * AK];

    const int m0  = blockIdx.x * 128;
    const int co0 = blockIdx.y * 64;
    const int tid = threadIdx.x;

    const int wave = tid >> 6;
    const int lane = tid & 63;
    const int r16  = lane & 15;
    const int quad = lane >> 4;
    const int mw   = wave * 32;

    f32x4 acc[2][4];
#pragma unroll
    for (int i = 0; i < 2; i++)
#pragma unroll
        for (int j = 0; j < 4; j++) acc[i][j] = (f32x4){0.f, 0.f, 0.f, 0.f};

    for (int k0 = 0; k0 < CCH; k0 += 32) {
#pragma unroll
        for (int l = 0; l < 4; l++) {
            int idx = tid + l * 256;
            int m = idx >> 3, kq = idx & 7;
            float4 v = *(const float4*)&x1[(size_t)(m0 + m) * CCH + k0 + kq * 4];
            short4 s;
            s.x = (short)f2bf(v.x); s.y = (short)f2bf(v.y);
            s.z = (short)f2bf(v.z); s.w = (short)f2bf(v.w);
            *(short4*)&As[m * AK + kq * 4] = s;
        }
#pragma unroll
        for (int l = 0; l < 8; l++) {
            int idx = tid + l * 256;
            int nn = idx & 63, kk = idx >> 6;
            int col = co0 + nn;
            float wv = 0.f;
            if (col < 144)      wv = w_off[(size_t)(k0 + kk) * 144 + col];
            else if (col < 216) wv = w_mask[(size_t)(k0 + kk) * 72 + col - 144];
            Ws[nn * AK + kk] = (short)f2bf(wv);
        }
        __syncthreads();

        bf16x8 a0 = *(const bf16x8*)&As[(mw + r16) * AK + quad * 8];
        bf16x8 a1 = *(const bf16x8*)&As[(mw + 16 + r16) * AK + quad * 8];
#pragma unroll
        for (int nt = 0; nt < 4; nt++) {
            bf16x8 bfr = *(const bf16x8*)&Ws[(nt * 16 + r16) * AK + quad * 8];
            acc[0][nt] = __builtin_amdgcn_mfma_f32_16x16x32_bf16(a0, bfr, acc[0][nt], 0, 0, 0);
            acc[1][nt] = __builtin_amdgcn_mfma_f32_16x16x32_bf16(a1, bfr, acc[1][nt], 0, 0, 0);
        }
        __syncthreads();
    }

#pragma unroll
    for (int nt = 0; nt < 4; nt++) {
        int col = co0 + nt * 16 + r16;
        if (col >= 216) continue;
        float bias = (col < 144) ? b_off[col] : b_mask[col - 144];
#pragma unroll
        for (int mt = 0; mt < 2; mt++) {
            int mbase = m0 + mw + mt * 16 + quad * 4;
#pragma unroll
            for (int r = 0; r < 4; r++) {
                int p = mbase + r;
                float v = acc[mt][nt][r] + bias;
                if (col < 144) off[(size_t)p * 144 + col] = v;
                else           msk[(size_t)p * 72 + col - 144] = v;
            }
        }
    }
}

// ---------------------------------------------------------------------------
// Kernel 4 (v2): deformable sampling + aggregation, 4 pixels/block
// Phase A: 32 threads -> softmax per (pix,g) into LDS
// Phase B: 288 entries -> clamped corner coords + premultiplied weights
// Phase C: lane owns 4 channels (float4); taps read from LDS (broadcast)
// ---------------------------------------------------------------------------
__global__ __launch_bounds__(256) void k_sample_agg(
    const float* __restrict__ xp, const float* __restrict__ off,
    const float* __restrict__ msk, float* __restrict__ agg)
{
    __shared__ float  sm[288];    // [pix][g][p] softmax probs
    __shared__ int2   tco[288];   // packed clamped corner coords
    __shared__ float4 twt[288];   // corner weights premult by mask

    const int tid = threadIdx.x;
    const int s0 = blockIdx.x * 4;

    // Phase A: softmax over 9 logits for each of 32 (pix,g) pairs
    if (tid < 32) {
        const int pix = tid >> 3, g = tid & 7;
        const float* mskp = msk + (size_t)(s0 + pix) * 72 + g * 9;
        float e[9];
        float mx = -1e30f;
#pragma unroll
        for (int p = 0; p < PP; p++) { e[p] = mskp[p]; mx = fmaxf(mx, e[p]); }
        float sum = 0.f;
#pragma unroll
        for (int p = 0; p < PP; p++) { e[p] = __expf(e[p] - mx); sum += e[p]; }
        float rs = 1.0f / sum;
#pragma unroll
        for (int p = 0; p < PP; p++) sm[tid * 9 + p] = e[p] * rs;
    }
    __syncthreads();

    // Phase B: per-(pix,g,p) tap precompute
    for (int idx = tid; idx < 288; idx += 256) {
        int pix = idx / 72;
        int rem = idx - pix * 72;
        int g = rem / 9;
        int p = rem - g * 9;
        int s = s0 + pix;
        int hw = s & 4095;
        int h = hw >> 6, w = hw & 63;
        const float* offp = off + (size_t)s * 144 + g * 18 + p * 2;
        float ox = offp[0], oy = offp[1];
        int i = p / 3, j = p - i * 3;          // i -> x offset, j -> y offset
        float fx = (float)(w + i) + ox;
        float fy = (float)(h + j) + oy;
        float x0f = floorf(fx), y0f = floorf(fy);
        int x0 = (int)x0f, y0 = (int)y0f;
        float wx = fx - x0f, wy = fy - y0f;
        float m = sm[idx];
        float w00 = (1.f - wx) * (1.f - wy) * m;
        float w10 = wx * (1.f - wy) * m;
        float w01 = (1.f - wx) * wy * m;
        float w11 = wx * wy * m;
        int x1c = x0 + 1, y1c = y0 + 1;
        if (!((x0  >= 0) && (x0  < WIN))) { w00 = 0.f; w01 = 0.f; }
        if (!((x1c >= 0) && (x1c < WIN))) { w10 = 0.f; w11 = 0.f; }
        if (!((y0  >= 0) && (y0  < HIN))) { w00 = 0.f; w10 = 0.f; }
        if (!((y1c >= 0) && (y1c < HIN))) { w01 = 0.f; w11 = 0.f; }
        int cx0 = min(max(x0, 0), WIN - 1), cx1 = min(max(x1c, 0), WIN - 1);
        int cy0 = min(max(y0, 0), HIN - 1), cy1 = min(max(y1c, 0), HIN - 1);
        tco[idx] = make_int2(cx0 | (cx1 << 16), cy0 | (cy1 << 16));
        twt[idx] = make_float4(w00, w10, w01, w11);
    }
    __syncthreads();

    // Phase C: wave = one pixel; lane = (g<<3)|c4; 4 channels per lane
    const int pix = tid >> 6;
    const int lane = tid & 63;
    const int g = lane >> 3, c4 = lane & 7;
    const int s = s0 + pix;
    const int n = s >> 12;
    const float* base = xp + (size_t)n * HIN * WIN * CCH + g * GCH + c4 * 4;
    const int tbase = pix * 72 + g * 9;

    float ax = 0.f, ay = 0.f, az = 0.f, aw = 0.f;
#pragma unroll
    for (int p = 0; p < PP; p++) {
        int2 cc = tco[tbase + p];
        float4 wt = twt[tbase + p];
        int cx0 = cc.x & 0xFFFF, cx1 = cc.x >> 16;
        int cy0 = cc.y & 0xFFFF, cy1 = cc.y >> 16;
        const float* r0 = base + (size_t)(cy0 * WIN) * CCH;
        const float* r1 = base + (size_t)(cy1 * WIN) * CCH;
        float4 v00 = *(const float4*)&r0[(size_t)cx0 * CCH];
        float4 v10 = *(const float4*)&r0[(size_t)cx1 * CCH];
        float4 v01 = *(const float4*)&r1[(size_t)cx0 * CCH];
        float4 v11 = *(const float4*)&r1[(size_t)cx1 * CCH];
        ax += wt.x * v00.x + wt.y * v10.x + wt.z * v01.x + wt.w * v11.x;
        ay += wt.x * v00.y + wt.y * v10.y + wt.z * v01.y + wt.w * v11.y;
        az += wt.x * v00.z + wt.y * v10.z + wt.z * v01.z + wt.w * v11.z;
        aw += wt.x * v00.w + wt.y * v10.w + wt.z * v01.w + wt.w * v11.w;
    }

    *(float4*)&agg[(size_t)s * CCH + g * GCH + c4 * 4] = make_float4(ax, ay, az, aw);
}

// ---------------------------------------------------------------------------
// Kernel 5: agg @ w_out + b_out -> BN -> SiLU -> out (NCHW), MFMA bf16
// ---------------------------------------------------------------------------
__global__ __launch_bounds__(256) void k_gemm_out(
    const float* __restrict__ agg, const float* __restrict__ w_out,
    const float* __restrict__ b_out, const float* __restrict__ bn_g,
    const float* __restrict__ bn_b, const float* __restrict__ bn_mean,
    const float* __restrict__ bn_var, float* __restrict__ out)
{
    __shared__ short As[128 * AK];
    __shared__ short Ws[64 * AK];

    const int m0  = blockIdx.x * 128;
    const int co0 = blockIdx.y * 64;
    const int tid = threadIdx.x;
    const int n   = m0 >> 12;
    const int hw0 = m0 & 4095;

    const int wave = tid >> 6;
    const int lane = tid & 63;
    const int r16  = lane & 15;
    const int quad = lane >> 4;
    const int mw   = wave * 32;

    f32x4 acc[2][4];
#pragma unroll
    for (int i = 0; i < 2; i++)
#pragma unroll
        for (int j = 0; j < 4; j++) acc[i][j] = (f32x4){0.f, 0.f, 0.f, 0.f};

    for (int k0 = 0; k0 < CCH; k0 += 32) {
#pragma unroll
        for (int l = 0; l < 4; l++) {
            int idx = tid + l * 256;
            int m = idx >> 3, kq = idx & 7;
            float4 v = *(const float4*)&agg[(size_t)(m0 + m) * CCH + k0 + kq * 4];
            short4 s;
            s.x = (short)f2bf(v.x); s.y = (short)f2bf(v.y);
            s.z = (short)f2bf(v.z); s.w = (short)f2bf(v.w);
            *(short4*)&As[m * AK + kq * 4] = s;
        }
#pragma unroll
        for (int l = 0; l < 8; l++) {
            int idx = tid + l * 256;
            int nn = idx & 63, kk = idx >> 6;
            Ws[nn * AK + kk] = (short)f2bf(w_out[(size_t)(k0 + kk) * CCH + co0 + nn]);
        }
        __syncthreads();

        bf16x8 a0 = *(const bf16x8*)&As[(mw + r16) * AK + quad * 8];
        bf16x8 a1 = *(const bf16x8*)&As[(mw + 16 + r16) * AK + quad * 8];
#pragma unroll
        for (int nt = 0; nt < 4; nt++) {
            bf16x8 bfr = *(const bf16x8*)&Ws[(nt * 16 + r16) * AK + quad * 8];
            acc[0][nt] = __builtin_amdgcn_mfma_f32_16x16x32_bf16(a0, bfr, acc[0][nt], 0, 0, 0);
            acc[1][nt] = __builtin_amdgcn_mfma_f32_16x16x32_bf16(a1, bfr, acc[1][nt], 0, 0, 0);
        }
        __syncthreads();
    }

#pragma unroll
    for (int nt = 0; nt < 4; nt++) {
        int co = co0 + nt * 16 + r16;
        float mean = bn_mean[co];
        float rstd = rsqrtf(bn_var[co] + 1e-5f);
        float gg = bn_g[co], bb = bn_b[co], bo = b_out[co];
#pragma unroll
        for (int mt = 0; mt < 2; mt++) {
            int hwb = hw0 + mw + mt * 16 + quad * 4;
            float tmp[4];
#pragma unroll
            for (int r = 0; r < 4; r++) {
                float y = acc[mt][nt][r] + bo;
                float yh = (y - mean) * rstd * gg + bb;
                tmp[r] = yh / (1.0f + __expf(-yh));
            }
            float4 v = make_float4(tmp[0], tmp[1], tmp[2], tmp[3]);
            *(float4*)&out[((size_t)n * CCH + co) * HWSZ + hwb] = v;
        }
    }
}

// ---------------------------------------------------------------------------
extern "C" void kernel_launch(void* const* d_in, const int* in_sizes, int n_in,
                              void* d_out, int out_size, void* d_ws, size_t ws_size,
                              hipStream_t stream)
{
    const float* x       = (const float*)d_in[0];
    const float* w_in    = (const float*)d_in[1];
    const float* b_in    = (const float*)d_in[2];
    const float* w_dw    = (const float*)d_in[3];
    const float* b_dw    = (const float*)d_in[4];
    const float* ln_g    = (const float*)d_in[5];
    const float* ln_b    = (const float*)d_in[6];
    const float* w_off   = (const float*)d_in[7];
    const float* b_off   = (const float*)d_in[8];
    const float* w_mask  = (const float*)d_in[9];
    const float* b_mask  = (const float*)d_in[10];
    const float* w_out   = (const float*)d_in[11];
    const float* b_out   = (const float*)d_in[12];
    const float* bn_g    = (const float*)d_in[13];
    const float* bn_b    = (const float*)d_in[14];
    const float* bn_mean = (const float*)d_in[15];
    const float* bn_var  = (const float*)d_in[16];
    float* out = (float*)d_out;

    float* ws  = (float*)d_ws;
    float* xp  = ws;
    float* x1  = xp + XP_ELEMS;
    float* off = x1 + X1_ELEMS;
    float* msk = off + OFF_ELEMS;
    float* agg = msk + MSK_ELEMS;

    k_zero_ring<<<dim3(1040), 64, 0, stream>>>(xp);
    k_gemm_in<<<dim3(128, 4), 256, 0, stream>>>(x, w_in, b_in, xp);
    k_dw_ln_gelu<<<dim3(2, 64, 4), 256, 0, stream>>>(x, w_dw, b_dw, ln_g, ln_b, x1);
    k_gemm_offmask<<<dim3(128, 4), 256, 0, stream>>>(x1, w_off, b_off, w_mask, b_mask, off, msk);
    k_sample_agg<<<dim3(4096), 256, 0, stream>>>(xp, off, msk, agg);
    k_gemm_out<<<dim3(128, 4), 256, 0, stream>>>(agg, w_out, b_out, bn_g, bn_b, bn_mean, bn_var, out);
}

// Round 4
// 219.804 us; speedup vs baseline: 1.8313x; 1.2254x over previous
//
#include <hip/hip_runtime.h>
#include <math.h>

// Problem constants
#define NB   4
#define CCH  256
#define HH   64
#define WW   64
#define GG   8
#define GCH  32
#define PP   9
#define HIN  66
#define WIN  66
#define HWSZ 4096            // H*W
#define NPIX 16384           // N*H*W

// Workspace layout (floats)
#define XP_ELEMS  (NB*HIN*WIN*CCH)      // 4460544
#define X1_ELEMS  (NPIX*CCH)            // 4194304
#define OFF_ELEMS (NPIX*144)            // 2359296
#define MSK_ELEMS (NPIX*72)             // 1179648
#define AGG_ELEMS (NPIX*CCH)            // 4194304

typedef __attribute__((ext_vector_type(8))) short bf16x8;
typedef __attribute__((ext_vector_type(4))) float f32x4;

__device__ __forceinline__ unsigned short f2bf(float f) {
    unsigned int u = __float_as_uint(f);
    unsigned int r = (u + 0x7FFFu + ((u >> 16) & 1u)) >> 16;
    return (unsigned short)r;
}
__device__ __forceinline__ float bf2f(unsigned short s) {
    unsigned int u = ((unsigned int)s) << 16;
    return __uint_as_float(u);
}

// LDS tile strides (bf16 elems): row = 32 k + 8 pad
#define AK 40

// ---------------------------------------------------------------------------
// Kernel 0: zero only the pad ring of xp (interior overwritten by k_gemm_in)
// ---------------------------------------------------------------------------
__global__ __launch_bounds__(64) void k_zero_ring(float* __restrict__ xp)
{
    int b = blockIdx.x;
    int n = b / 260;
    int rp = b % 260;
    int h, w;
    if (rp < 66)       { h = 0;        w = rp; }
    else if (rp < 132) { h = 65;       w = rp - 66; }
    else if (rp < 196) { h = rp - 131; w = 0; }    // h = 1..64
    else               { h = rp - 195; w = 65; }   // h = 1..64
    float4 z = make_float4(0.f, 0.f, 0.f, 0.f);
    *(float4*)&xp[(((size_t)n * HIN + h) * WIN + w) * CCH + threadIdx.x * 4] = z;
}

// ---------------------------------------------------------------------------
// Kernel 1: input projection  x(NCHW) @ w_in -> xp (padded channels-last)
// MFMA bf16: block tile 128(m) x 64(n), BK=32, 4 waves x (2 mt x 4 nt)
// ---------------------------------------------------------------------------
__global__ __launch_bounds__(256) void k_gemm_in(
    const float* __restrict__ x, const float* __restrict__ w_in,
    const float* __restrict__ b_in, float* __restrict__ xp)
{
    __shared__ short As[128 * AK];
    __shared__ short Ws[64 * AK];

    const int m0  = blockIdx.x * 128;
    const int co0 = blockIdx.y * 64;
    const int tid = threadIdx.x;
    const int n   = m0 >> 12;
    const int hw0 = m0 & 4095;

    const int wave = tid >> 6;
    const int lane = tid & 63;
    const int r16  = lane & 15;
    const int quad = lane >> 4;
    const int mw   = wave * 32;

    const float* xa = x + (size_t)n * CCH * HWSZ + hw0;

    f32x4 acc[2][4];
#pragma unroll
    for (int i = 0; i < 2; i++)
#pragma unroll
        for (int j = 0; j < 4; j++) acc[i][j] = (f32x4){0.f, 0.f, 0.f, 0.f};

    for (int k0 = 0; k0 < CCH; k0 += 32) {
#pragma unroll
        for (int l = 0; l < 16; l++) {
            int idx = tid + l * 256;
            int kk = idx >> 7, m = idx & 127;
            As[m * AK + kk] = (short)f2bf(xa[(size_t)(k0 + kk) * HWSZ + m]);
        }
#pragma unroll
        for (int l = 0; l < 8; l++) {
            int idx = tid + l * 256;
            int nn = idx & 63, kk = idx >> 6;
            Ws[nn * AK + kk] = (short)f2bf(w_in[(size_t)(k0 + kk) * CCH + co0 + nn]);
        }
        __syncthreads();

        bf16x8 a0 = *(const bf16x8*)&As[(mw + r16) * AK + quad * 8];
        bf16x8 a1 = *(const bf16x8*)&As[(mw + 16 + r16) * AK + quad * 8];
#pragma unroll
        for (int nt = 0; nt < 4; nt++) {
            bf16x8 bfr = *(const bf16x8*)&Ws[(nt * 16 + r16) * AK + quad * 8];
            acc[0][nt] = __builtin_amdgcn_mfma_f32_16x16x32_bf16(a0, bfr, acc[0][nt], 0, 0, 0);
            acc[1][nt] = __builtin_amdgcn_mfma_f32_16x16x32_bf16(a1, bfr, acc[1][nt], 0, 0, 0);
        }
        __syncthreads();
    }

#pragma unroll
    for (int nt = 0; nt < 4; nt++) {
        int co = co0 + nt * 16 + r16;
        float bias = b_in[co];
#pragma unroll
        for (int mt = 0; mt < 2; mt++) {
            int mbase = mw + mt * 16 + quad * 4;
#pragma unroll
            for (int r = 0; r < 4; r++) {
                int hw = hw0 + mbase + r;
                int h = hw >> 6, w = hw & 63;
                xp[(((size_t)n * HIN + (h + 1)) * WIN + (w + 1)) * CCH + co] =
                    acc[mt][nt][r] + bias;
            }
        }
    }
}

// ---------------------------------------------------------------------------
// Kernel 2 (v2): depthwise 3x3 + bias + LayerNorm(C) + exact GELU -> x1
// One block per (n,h): 512 threads = 8 waves; wave=channel, lane=w.
// 3 coalesced row loads per channel; w+-1 via shuffles; LN sums in regs;
// conv values parked in LDS as bf16 (stride 258, conflict-free).
// ---------------------------------------------------------------------------
#define SDW_STRIDE 258
__global__ __launch_bounds__(512) void k_dw_ln_gelu(
    const float* __restrict__ x, const float* __restrict__ w_dw,
    const float* __restrict__ b_dw, const float* __restrict__ ln_g,
    const float* __restrict__ ln_b, float* __restrict__ x1)
{
    __shared__ unsigned short sdw[64 * SDW_STRIDE];   // [w][c] bf16
    __shared__ float r1s[8][64];
    __shared__ float r2s[8][64];
    __shared__ float mu_s[64];
    __shared__ float rs_s[64];

    const int h = blockIdx.x;
    const int n = blockIdx.y;
    const int tid = threadIdx.x;
    const int wave = tid >> 6;
    const int lane = tid & 63;        // = w in phase 1

    const float* xn = x + (size_t)n * CCH * HWSZ;
    const bool h0ok = (h > 0);
    const bool h2ok = (h < HH - 1);

    float s1 = 0.f, s2 = 0.f;

#pragma unroll 4
    for (int it = 0; it < 32; it++) {
        const int c = it * 8 + wave;
        const float* xc = xn + (size_t)c * HWSZ + h * WW + lane;
        float v0 = h0ok ? xc[-WW] : 0.f;
        float v1 = xc[0];
        float v2 = h2ok ? xc[WW] : 0.f;

        const float* wk = w_dw + c * 9;
        float acc = b_dw[c];

        float l0 = __shfl_up(v0, 1);  if (lane == 0)  l0 = 0.f;
        float r0 = __shfl_down(v0, 1); if (lane == 63) r0 = 0.f;
        acc += wk[0] * l0 + wk[1] * v0 + wk[2] * r0;

        float l1 = __shfl_up(v1, 1);  if (lane == 0)  l1 = 0.f;
        float r1 = __shfl_down(v1, 1); if (lane == 63) r1 = 0.f;
        acc += wk[3] * l1 + wk[4] * v1 + wk[5] * r1;

        float l2 = __shfl_up(v2, 1);  if (lane == 0)  l2 = 0.f;
        float r2 = __shfl_down(v2, 1); if (lane == 63) r2 = 0.f;
        acc += wk[6] * l2 + wk[7] * v2 + wk[8] * r2;

        s1 += acc;
        s2 += acc * acc;
        sdw[lane * SDW_STRIDE + c] = f2bf(acc);
    }

    r1s[wave][lane] = s1;
    r2s[wave][lane] = s2;
    __syncthreads();

    if (tid < 64) {
        float a1 = 0.f, a2 = 0.f;
#pragma unroll
        for (int q = 0; q < 8; q++) { a1 += r1s[q][tid]; a2 += r2s[q][tid]; }
        float mu = a1 * (1.0f / 256.0f);
        float var = a2 * (1.0f / 256.0f) - mu * mu;
        mu_s[tid] = mu;
        rs_s[tid] = rsqrtf(var + 1e-5f);
    }
    __syncthreads();

    // Phase 3: normalize + GELU; lane covers channels (coalesced x1 writes)
    const int c0 = (tid & 63) * 4;
    const int wq = tid >> 6;          // 0..7
    float g4[4], b4[4];
#pragma unroll
    for (int i = 0; i < 4; i++) { g4[i] = ln_g[c0 + i]; b4[i] = ln_b[c0 + i]; }

    float* x1p = x1 + (((size_t)n * HH + h) * WW) * CCH + c0;
#pragma unroll
    for (int pass = 0; pass < 8; pass++) {
        int w = wq + pass * 8;
        float mu = mu_s[w], rs = rs_s[w];
        const unsigned short* row = &sdw[w * SDW_STRIDE + c0];
        float tmp[4];
#pragma unroll
        for (int i = 0; i < 4; i++) {
            float v = (bf2f(row[i]) - mu) * rs * g4[i] + b4[i];
            tmp[i] = 0.5f * v * (1.0f + erff(v * 0.70710678118654752f));
        }
        *(float4*)&x1p[(size_t)w * CCH] = make_float4(tmp[0], tmp[1], tmp[2], tmp[3]);
    }
}

// ---------------------------------------------------------------------------
// Kernel 3: x1 @ [w_off | w_mask] + bias -> off (16384x144), msk (16384x72)
// ---------------------------------------------------------------------------
__global__ __launch_bounds__(256) void k_gemm_offmask(
    const float* __restrict__ x1, const float* __restrict__ w_off,
    const float* __restrict__ b_off, const float* __restrict__ w_mask,
    const float* __restrict__ b_mask, float* __restrict__ off,
    float* __restrict__ msk)
{
    __shared__ short As[128 * AK];
    __shared__ short Ws[64 * AK];

    const int m0  = blockIdx.x * 128;
    const int co0 = blockIdx.y * 64;
    const int tid = threadIdx.x;

    const int wave = tid >> 6;
    const int lane = tid & 63;
    const int r16  = lane & 15;
    const int quad = lane >> 4;
    const int mw   = wave * 32;

    f32x4 acc[2][4];
#pragma unroll
    for (int i = 0; i < 2; i++)
#pragma unroll
        for (int j = 0; j < 4; j++) acc[i][j] = (f32x4){0.f, 0.f, 0.f, 0.f};

    for (int k0 = 0; k0 < CCH; k0 += 32) {
#pragma unroll
        for (int l = 0; l < 4; l++) {
            int idx = tid + l * 256;
            int m = idx >> 3, kq = idx & 7;
            float4 v = *(const float4*)&x1[(size_t)(m0 + m) * CCH + k0 + kq * 4];
            short4 s;
            s.x = (short)f2bf(v.x); s.y = (short)f2bf(v.y);
            s.z = (short)f2bf(v.z); s.w = (short)f2bf(v.w);
            *(short4*)&As[m * AK + kq * 4] = s;
        }
#pragma unroll
        for (int l = 0; l < 8; l++) {
            int idx = tid + l * 256;
            int nn = idx & 63, kk = idx >> 6;
            int col = co0 + nn;
            float wv = 0.f;
            if (col < 144)      wv = w_off[(size_t)(k0 + kk) * 144 + col];
            else if (col < 216) wv = w_mask[(size_t)(k0 + kk) * 72 + col - 144];
            Ws[nn * AK + kk] = (short)f2bf(wv);
        }
        __syncthreads();

        bf16x8 a0 = *(const bf16x8*)&As[(mw + r16) * AK + quad * 8];
        bf16x8 a1 = *(const bf16x8*)&As[(mw + 16 + r16) * AK + quad * 8];
#pragma unroll
        for (int nt = 0; nt < 4; nt++) {
            bf16x8 bfr = *(const bf16x8*)&Ws[(nt * 16 + r16) * AK + quad * 8];
            acc[0][nt] = __builtin_amdgcn_mfma_f32_16x16x32_bf16(a0, bfr, acc[0][nt], 0, 0, 0);
            acc[1][nt] = __builtin_amdgcn_mfma_f32_16x16x32_bf16(a1, bfr, acc[1][nt], 0, 0, 0);
        }
        __syncthreads();
    }

#pragma unroll
    for (int nt = 0; nt < 4; nt++) {
        int col = co0 + nt * 16 + r16;
        if (col >= 216) continue;
        float bias = (col < 144) ? b_off[col] : b_mask[col - 144];
#pragma unroll
        for (int mt = 0; mt < 2; mt++) {
            int mbase = m0 + mw + mt * 16 + quad * 4;
#pragma unroll
            for (int r = 0; r < 4; r++) {
                int p = mbase + r;
                float v = acc[mt][nt][r] + bias;
                if (col < 144) off[(size_t)p * 144 + col] = v;
                else           msk[(size_t)p * 72 + col - 144] = v;
            }
        }
    }
}

// ---------------------------------------------------------------------------
// Kernel 4: deformable sampling + aggregation, 4 pixels/block
// ---------------------------------------------------------------------------
__global__ __launch_bounds__(256) void k_sample_agg(
    const float* __restrict__ xp, const float* __restrict__ off,
    const float* __restrict__ msk, float* __restrict__ agg)
{
    __shared__ float  sm[288];
    __shared__ int2   tco[288];
    __shared__ float4 twt[288];

    const int tid = threadIdx.x;
    const int s0 = blockIdx.x * 4;

    if (tid < 32) {
        const int pix = tid >> 3, g = tid & 7;
        const float* mskp = msk + (size_t)(s0 + pix) * 72 + g * 9;
        float e[9];
        float mx = -1e30f;
#pragma unroll
        for (int p = 0; p < PP; p++) { e[p] = mskp[p]; mx = fmaxf(mx, e[p]); }
        float sum = 0.f;
#pragma unroll
        for (int p = 0; p < PP; p++) { e[p] = __expf(e[p] - mx); sum += e[p]; }
        float rs = 1.0f / sum;
#pragma unroll
        for (int p = 0; p < PP; p++) sm[tid * 9 + p] = e[p] * rs;
    }
    __syncthreads();

    for (int idx = tid; idx < 288; idx += 256) {
        int pix = idx / 72;
        int rem = idx - pix * 72;
        int g = rem / 9;
        int p = rem - g * 9;
        int s = s0 + pix;
        int hw = s & 4095;
        int h = hw >> 6, w = hw & 63;
        const float* offp = off + (size_t)s * 144 + g * 18 + p * 2;
        float ox = offp[0], oy = offp[1];
        int i = p / 3, j = p - i * 3;
        float fx = (float)(w + i) + ox;
        float fy = (float)(h + j) + oy;
        float x0f = floorf(fx), y0f = floorf(fy);
        int x0 = (int)x0f, y0 = (int)y0f;
        float wx = fx - x0f, wy = fy - y0f;
        float m = sm[idx];
        float w00 = (1.f - wx) * (1.f - wy) * m;
        float w10 = wx * (1.f - wy) * m;
        float w01 = (1.f - wx) * wy * m;
        float w11 = wx * wy * m;
        int x1c = x0 + 1, y1c = y0 + 1;
        if (!((x0  >= 0) && (x0  < WIN))) { w00 = 0.f; w01 = 0.f; }
        if (!((x1c >= 0) && (x1c < WIN))) { w10 = 0.f; w11 = 0.f; }
        if (!((y0  >= 0) && (y0  < HIN))) { w00 = 0.f; w10 = 0.f; }
        if (!((y1c >= 0) && (y1c < HIN))) { w01 = 0.f; w11 = 0.f; }
        int cx0 = min(max(x0, 0), WIN - 1), cx1 = min(max(x1c, 0), WIN - 1);
        int cy0 = min(max(y0, 0), HIN - 1), cy1 = min(max(y1c, 0), HIN - 1);
        tco[idx] = make_int2(cx0 | (cx1 << 16), cy0 | (cy1 << 16));
        twt[idx] = make_float4(w00, w10, w01, w11);
    }
    __syncthreads();

    const int pix = tid >> 6;
    const int lane = tid & 63;
    const int g = lane >> 3, c4 = lane & 7;
    const int s = s0 + pix;
    const int n = s >> 12;
    const float* base = xp + (size_t)n * HIN * WIN * CCH + g * GCH + c4 * 4;
    const int tbase = pix * 72 + g * 9;

    float ax = 0.f, ay = 0.f, az = 0.f, aw = 0.f;
#pragma unroll
    for (int p = 0; p < PP; p++) {
        int2 cc = tco[tbase + p];
        float4 wt = twt[tbase + p];
        int cx0 = cc.x & 0xFFFF, cx1 = cc.x >> 16;
        int cy0 = cc.y & 0xFFFF, cy1 = cc.y >> 16;
        const float* r0 = base + (size_t)(cy0 * WIN) * CCH;
        const float* r1 = base + (size_t)(cy1 * WIN) * CCH;
        float4 v00 = *(const float4*)&r0[(size_t)cx0 * CCH];
        float4 v10 = *(const float4*)&r0[(size_t)cx1 * CCH];
        float4 v01 = *(const float4*)&r1[(size_t)cx0 * CCH];
        float4 v11 = *(const float4*)&r1[(size_t)cx1 * CCH];
        ax += wt.x * v00.x + wt.y * v10.x + wt.z * v01.x + wt.w * v11.x;
        ay += wt.x * v00.y + wt.y * v10.y + wt.z * v01.y + wt.w * v11.y;
        az += wt.x * v00.z + wt.y * v10.z + wt.z * v01.z + wt.w * v11.z;
        aw += wt.x * v00.w + wt.y * v10.w + wt.z * v01.w + wt.w * v11.w;
    }

    *(float4*)&agg[(size_t)s * CCH + g * GCH + c4 * 4] = make_float4(ax, ay, az, aw);
}

// ---------------------------------------------------------------------------
// Kernel 5: agg @ w_out + b_out -> BN -> SiLU -> out (NCHW), MFMA bf16
// ---------------------------------------------------------------------------
__global__ __launch_bounds__(256) void k_gemm_out(
    const float* __restrict__ agg, const float* __restrict__ w_out,
    const float* __restrict__ b_out, const float* __restrict__ bn_g,
    const float* __restrict__ bn_b, const float* __restrict__ bn_mean,
    const float* __restrict__ bn_var, float* __restrict__ out)
{
    __shared__ short As[128 * AK];
    __shared__ short Ws[64 * AK];

    const int m0  = blockIdx.x * 128;
    const int co0 = blockIdx.y * 64;
    const int tid = threadIdx.x;
    const int n   = m0 >> 12;
    const int hw0 = m0 & 4095;

    const int wave = tid >> 6;
    const int lane = tid & 63;
    const int r16  = lane & 15;
    const int quad = lane >> 4;
    const int mw   = wave * 32;

    f32x4 acc[2][4];
#pragma unroll
    for (int i = 0; i < 2; i++)
#pragma unroll
        for (int j = 0; j < 4; j++) acc[i][j] = (f32x4){0.f, 0.f, 0.f, 0.f};

    for (int k0 = 0; k0 < CCH; k0 += 32) {
#pragma unroll
        for (int l = 0; l < 4; l++) {
            int idx = tid + l * 256;
            int m = idx >> 3, kq = idx & 7;
            float4 v = *(const float4*)&agg[(size_t)(m0 + m) * CCH + k0 + kq * 4];
            short4 s;
            s.x = (short)f2bf(v.x); s.y = (short)f2bf(v.y);
            s.z = (short)f2bf(v.z); s.w = (short)f2bf(v.w);
            *(short4*)&As[m * AK + kq * 4] = s;
        }
#pragma unroll
        for (int l = 0; l < 8; l++) {
            int idx = tid + l * 256;
            int nn = idx & 63, kk = idx >> 6;
            Ws[nn * AK + kk] = (short)f2bf(w_out[(size_t)(k0 + kk) * CCH + co0 + nn]);
        }
        __syncthreads();

        bf16x8 a0 = *(const bf16x8*)&As[(mw + r16) * AK + quad * 8];
        bf16x8 a1 = *(const bf16x8*)&As[(mw + 16 + r16) * AK + quad * 8];
#pragma unroll
        for (int nt = 0; nt < 4; nt++) {
            bf16x8 bfr = *(const bf16x8*)&Ws[(nt * 16 + r16) * AK + quad * 8];
            acc[0][nt] = __builtin_amdgcn_mfma_f32_16x16x32_bf16(a0, bfr, acc[0][nt], 0, 0, 0);
            acc[1][nt] = __builtin_amdgcn_mfma_f32_16x16x32_bf16(a1, bfr, acc[1][nt], 0, 0, 0);
        }
        __syncthreads();
    }

#pragma unroll
    for (int nt = 0; nt < 4; nt++) {
        int co = co0 + nt * 16 + r16;
        float mean = bn_mean[co];
        float rstd = rsqrtf(bn_var[co] + 1e-5f);
        float gg = bn_g[co], bb = bn_b[co], bo = b_out[co];
#pragma unroll
        for (int mt = 0; mt < 2; mt++) {
            int hwb = hw0 + mw + mt * 16 + quad * 4;
            float tmp[4];
#pragma unroll
            for (int r = 0; r < 4; r++) {
                float y = acc[mt][nt][r] + bo;
                float yh = (y - mean) * rstd * gg + bb;
                tmp[r] = yh / (1.0f + __expf(-yh));
            }
            float4 v = make_float4(tmp[0], tmp[1], tmp[2], tmp[3]);
            *(float4*)&out[((size_t)n * CCH + co) * HWSZ + hwb] = v;
        }
    }
}

// ---------------------------------------------------------------------------
extern "C" void kernel_launch(void* const* d_in, const int* in_sizes, int n_in,
                              void* d_out, int out_size, void* d_ws, size_t ws_size,
                              hipStream_t stream)
{
    const float* x       = (const float*)d_in[0];
    const float* w_in    = (const float*)d_in[1];
    const float* b_in    = (const float*)d_in[2];
    const float* w_dw    = (const float*)d_in[3];
    const float* b_dw    = (const float*)d_in[4];
    const float* ln_g    = (const float*)d_in[5];
    const float* ln_b    = (const float*)d_in[6];
    const float* w_off   = (const float*)d_in[7];
    const float* b_off   = (const float*)d_in[8];
    const float* w_mask  = (const float*)d_in[9];
    const float* b_mask  = (const float*)d_in[10];
    const float* w_out   = (const float*)d_in[11];
    const float* b_out   = (const float*)d_in[12];
    const float* bn_g    = (const float*)d_in[13];
    const float* bn_b    = (const float*)d_in[14];
    const float* bn_mean = (const float*)d_in[15];
    const float* bn_var  = (const float*)d_in[16];
    float* out = (float*)d_out;

    float* ws  = (float*)d_ws;
    float* xp  = ws;
    float* x1  = xp + XP_ELEMS;
    float* off = x1 + X1_ELEMS;
    float* msk = off + OFF_ELEMS;
    float* agg = msk + MSK_ELEMS;

    k_zero_ring<<<dim3(1040), 64, 0, stream>>>(xp);
    k_gemm_in<<<dim3(128, 4), 256, 0, stream>>>(x, w_in, b_in, xp);
    k_dw_ln_gelu<<<dim3(64, 4), 512, 0, stream>>>(x, w_dw, b_dw, ln_g, ln_b, x1);
    k_gemm_offmask<<<dim3(128, 4), 256, 0, stream>>>(x1, w_off, b_off, w_mask, b_mask, off, msk);
    k_sample_agg<<<dim3(4096), 256, 0, stream>>>(xp, off, msk, agg);
    k_gemm_out<<<dim3(128, 4), 256, 0, stream>>>(agg, w_out, b_out, bn_g, bn_b, bn_mean, bn_var, out);
}

// Round 5
// 181.504 us; speedup vs baseline: 2.2178x; 1.2110x over previous
//
#include <hip/hip_runtime.h>
#include <math.h>

// Problem constants
#define NB   4
#define CCH  256
#define HH   64
#define WW   64
#define GG   8
#define GCH  32
#define PP   9
#define HIN  66
#define WIN  66
#define HWSZ 4096            // H*W
#define NPIX 16384           // N*H*W

// Workspace element counts
#define XP_ELEMS  (NB*HIN*WIN*CCH)      // 4460544  (ushort/bf16)
#define X1_ELEMS  (NPIX*CCH)            // 4194304  (ushort/bf16)
#define AGG_ELEMS (NPIX*CCH)            // 4194304  (ushort/bf16)
#define OFF_ELEMS (NPIX*144)            // 2359296  (float)
#define MSK_ELEMS (NPIX*72)             // 1179648  (float)

typedef __attribute__((ext_vector_type(8))) short bf16x8;
typedef __attribute__((ext_vector_type(4))) float f32x4;

__device__ __forceinline__ unsigned short f2bf(float f) {
    unsigned int u = __float_as_uint(f);
    unsigned int r = (u + 0x7FFFu + ((u >> 16) & 1u)) >> 16;
    return (unsigned short)r;
}
__device__ __forceinline__ float bf2f(unsigned short s) {
    return __uint_as_float(((unsigned int)s) << 16);
}
__device__ __forceinline__ unsigned int f2bf_pk(float lo, float hi) {
    return (unsigned int)f2bf(lo) | ((unsigned int)f2bf(hi) << 16);
}

// LDS row stride (bf16 elems): 32 k + 8 pad = 80 B (16-B aligned, 2-way banks)
#define AK 40

// ---------------------------------------------------------------------------
// Kernel 0: zero only the pad ring of xp (bf16)
// ---------------------------------------------------------------------------
__global__ __launch_bounds__(64) void k_zero_ring(unsigned short* __restrict__ xp)
{
    int b = blockIdx.x;
    int n = b / 260;
    int rp = b % 260;
    int h, w;
    if (rp < 66)       { h = 0;        w = rp; }
    else if (rp < 132) { h = 65;       w = rp - 66; }
    else if (rp < 196) { h = rp - 131; w = 0; }    // h = 1..64
    else               { h = rp - 195; w = 65; }   // h = 1..64
    uint2 z = make_uint2(0u, 0u);
    *(uint2*)&xp[(((size_t)n * HIN + h) * WIN + w) * CCH + threadIdx.x * 4] = z;
}

// ---------------------------------------------------------------------------
// Kernel 1: input projection  x(NCHW fp32) @ w_in -> xp (padded ch-last bf16)
// MFMA bf16: block tile 128(m) x 64(n), BK=32; staging packs 2 k per b32
// ---------------------------------------------------------------------------
__global__ __launch_bounds__(256) void k_gemm_in(
    const float* __restrict__ x, const float* __restrict__ w_in,
    const float* __restrict__ b_in, unsigned short* __restrict__ xp)
{
    __shared__ short As[128 * AK];
    __shared__ short Ws[64 * AK];

    const int m0  = blockIdx.x * 128;
    const int co0 = blockIdx.y * 64;
    const int tid = threadIdx.x;
    const int n   = m0 >> 12;
    const int hw0 = m0 & 4095;

    const int wave = tid >> 6;
    const int lane = tid & 63;
    const int r16  = lane & 15;
    const int quad = lane >> 4;
    const int mw   = wave * 32;

    const float* xa = x + (size_t)n * CCH * HWSZ + hw0;

    f32x4 acc[2][4];
#pragma unroll
    for (int i = 0; i < 2; i++)
#pragma unroll
        for (int j = 0; j < 4; j++) acc[i][j] = (f32x4){0.f, 0.f, 0.f, 0.f};

    for (int k0 = 0; k0 < CCH; k0 += 32) {
        // stage A: 128 m x 32 k, coalesced along m, 2 k packed per b32 write
#pragma unroll
        for (int l = 0; l < 8; l++) {
            int idx = tid + l * 256;
            int m = idx & 127, kp = idx >> 7;      // kp = k/2, 0..15
            float v0 = xa[(size_t)(k0 + 2 * kp) * HWSZ + m];
            float v1 = xa[(size_t)(k0 + 2 * kp + 1) * HWSZ + m];
            ((unsigned int*)As)[(m * AK) / 2 + kp] = f2bf_pk(v0, v1);
        }
        // stage W: 32 k x 64 n, coalesced along n, 2 k packed per b32 write
#pragma unroll
        for (int l = 0; l < 4; l++) {
            int idx = tid + l * 256;
            int nn = idx & 63, kp = idx >> 6;      // 0..15
            float v0 = w_in[(size_t)(k0 + 2 * kp) * CCH + co0 + nn];
            float v1 = w_in[(size_t)(k0 + 2 * kp + 1) * CCH + co0 + nn];
            ((unsigned int*)Ws)[(nn * AK) / 2 + kp] = f2bf_pk(v0, v1);
        }
        __syncthreads();

        bf16x8 a0 = *(const bf16x8*)&As[(mw + r16) * AK + quad * 8];
        bf16x8 a1 = *(const bf16x8*)&As[(mw + 16 + r16) * AK + quad * 8];
#pragma unroll
        for (int nt = 0; nt < 4; nt++) {
            bf16x8 bfr = *(const bf16x8*)&Ws[(nt * 16 + r16) * AK + quad * 8];
            acc[0][nt] = __builtin_amdgcn_mfma_f32_16x16x32_bf16(a0, bfr, acc[0][nt], 0, 0, 0);
            acc[1][nt] = __builtin_amdgcn_mfma_f32_16x16x32_bf16(a1, bfr, acc[1][nt], 0, 0, 0);
        }
        __syncthreads();
    }

#pragma unroll
    for (int nt = 0; nt < 4; nt++) {
        int co = co0 + nt * 16 + r16;
        float bias = b_in[co];
#pragma unroll
        for (int mt = 0; mt < 2; mt++) {
            int mbase = mw + mt * 16 + quad * 4;
#pragma unroll
            for (int r = 0; r < 4; r++) {
                int hw = hw0 + mbase + r;
                int h = hw >> 6, w = hw & 63;
                xp[(((size_t)n * HIN + (h + 1)) * WIN + (w + 1)) * CCH + co] =
                    f2bf(acc[mt][nt][r] + bias);
            }
        }
    }
}

// ---------------------------------------------------------------------------
// Kernel 2: depthwise 3x3 + bias + LayerNorm(C) + exact GELU -> x1 (bf16)
// One block per (n,h): 512 threads = 8 waves; wave=channel, lane=w.
// ---------------------------------------------------------------------------
#define SDW_STRIDE 258
__global__ __launch_bounds__(512) void k_dw_ln_gelu(
    const float* __restrict__ x, const float* __restrict__ w_dw,
    const float* __restrict__ b_dw, const float* __restrict__ ln_g,
    const float* __restrict__ ln_b, unsigned short* __restrict__ x1)
{
    __shared__ unsigned short sdw[64 * SDW_STRIDE];   // [w][c] bf16
    __shared__ float r1s[8][64];
    __shared__ float r2s[8][64];
    __shared__ float mu_s[64];
    __shared__ float rs_s[64];

    const int h = blockIdx.x;
    const int n = blockIdx.y;
    const int tid = threadIdx.x;
    const int wave = tid >> 6;
    const int lane = tid & 63;        // = w in phase 1

    const float* xn = x + (size_t)n * CCH * HWSZ;
    const bool h0ok = (h > 0);
    const bool h2ok = (h < HH - 1);

    float s1 = 0.f, s2 = 0.f;

#pragma unroll 4
    for (int it = 0; it < 32; it++) {
        const int c = it * 8 + wave;
        const float* xc = xn + (size_t)c * HWSZ + h * WW + lane;
        float v0 = h0ok ? xc[-WW] : 0.f;
        float v1 = xc[0];
        float v2 = h2ok ? xc[WW] : 0.f;

        const float* wk = w_dw + c * 9;
        float acc = b_dw[c];

        float l0 = __shfl_up(v0, 1);  if (lane == 0)  l0 = 0.f;
        float r0 = __shfl_down(v0, 1); if (lane == 63) r0 = 0.f;
        acc += wk[0] * l0 + wk[1] * v0 + wk[2] * r0;

        float l1 = __shfl_up(v1, 1);  if (lane == 0)  l1 = 0.f;
        float r1 = __shfl_down(v1, 1); if (lane == 63) r1 = 0.f;
        acc += wk[3] * l1 + wk[4] * v1 + wk[5] * r1;

        float l2 = __shfl_up(v2, 1);  if (lane == 0)  l2 = 0.f;
        float r2 = __shfl_down(v2, 1); if (lane == 63) r2 = 0.f;
        acc += wk[6] * l2 + wk[7] * v2 + wk[8] * r2;

        s1 += acc;
        s2 += acc * acc;
        sdw[lane * SDW_STRIDE + c] = f2bf(acc);
    }

    r1s[wave][lane] = s1;
    r2s[wave][lane] = s2;
    __syncthreads();

    if (tid < 64) {
        float a1 = 0.f, a2 = 0.f;
#pragma unroll
        for (int q = 0; q < 8; q++) { a1 += r1s[q][tid]; a2 += r2s[q][tid]; }
        float mu = a1 * (1.0f / 256.0f);
        float var = a2 * (1.0f / 256.0f) - mu * mu;
        mu_s[tid] = mu;
        rs_s[tid] = rsqrtf(var + 1e-5f);
    }
    __syncthreads();

    // Phase 3: normalize + GELU; write bf16 channels-last (coalesced)
    const int c0 = (tid & 63) * 4;
    const int wq = tid >> 6;          // 0..7
    float g4[4], b4[4];
#pragma unroll
    for (int i = 0; i < 4; i++) { g4[i] = ln_g[c0 + i]; b4[i] = ln_b[c0 + i]; }

    unsigned short* x1p = x1 + (((size_t)n * HH + h) * WW) * CCH + c0;
#pragma unroll
    for (int pass = 0; pass < 8; pass++) {
        int w = wq + pass * 8;
        float mu = mu_s[w], rs = rs_s[w];
        const unsigned short* row = &sdw[w * SDW_STRIDE + c0];
        unsigned short tmp[4];
#pragma unroll
        for (int i = 0; i < 4; i++) {
            float v = (bf2f(row[i]) - mu) * rs * g4[i] + b4[i];
            tmp[i] = f2bf(0.5f * v * (1.0f + erff(v * 0.70710678118654752f)));
        }
        ushort4 o; o.x = tmp[0]; o.y = tmp[1]; o.z = tmp[2]; o.w = tmp[3];
        *(ushort4*)&x1p[(size_t)w * CCH] = o;
    }
}

// ---------------------------------------------------------------------------
// Kernel 3: x1(bf16) @ [w_off | w_mask] + bias -> off, msk (fp32)
// A staged via uint4 (8 bf16) loads + ds_write_b128 (no convert)
// ---------------------------------------------------------------------------
__global__ __launch_bounds__(256) void k_gemm_offmask(
    const unsigned short* __restrict__ x1, const float* __restrict__ w_off,
    const float* __restrict__ b_off, const float* __restrict__ w_mask,
    const float* __restrict__ b_mask, float* __restrict__ off,
    float* __restrict__ msk)
{
    __shared__ short As[128 * AK];
    __shared__ short Ws[64 * AK];

    const int m0  = blockIdx.x * 128;
    const int co0 = blockIdx.y * 64;
    const int tid = threadIdx.x;

    const int wave = tid >> 6;
    const int lane = tid & 63;
    const int r16  = lane & 15;
    const int quad = lane >> 4;
    const int mw   = wave * 32;

    f32x4 acc[2][4];
#pragma unroll
    for (int i = 0; i < 2; i++)
#pragma unroll
        for (int j = 0; j < 4; j++) acc[i][j] = (f32x4){0.f, 0.f, 0.f, 0.f};

    for (int k0 = 0; k0 < CCH; k0 += 32) {
        // stage A: 128 m x 32 k bf16, 16 B per thread-pass
#pragma unroll
        for (int l = 0; l < 2; l++) {
            int idx = tid + l * 256;
            int m = idx >> 2, kq = idx & 3;
            uint4 v = *(const uint4*)&x1[(size_t)(m0 + m) * CCH + k0 + kq * 8];
            *(uint4*)&As[m * AK + kq * 8] = v;
        }
        // stage W (concat w_off|w_mask), 2 k packed per b32
#pragma unroll
        for (int l = 0; l < 4; l++) {
            int idx = tid + l * 256;
            int nn = idx & 63, kp = idx >> 6;
            int col = co0 + nn;
            float v0 = 0.f, v1 = 0.f;
            if (col < 144) {
                v0 = w_off[(size_t)(k0 + 2 * kp) * 144 + col];
                v1 = w_off[(size_t)(k0 + 2 * kp + 1) * 144 + col];
            } else if (col < 216) {
                v0 = w_mask[(size_t)(k0 + 2 * kp) * 72 + col - 144];
                v1 = w_mask[(size_t)(k0 + 2 * kp + 1) * 72 + col - 144];
            }
            ((unsigned int*)Ws)[(nn * AK) / 2 + kp] = f2bf_pk(v0, v1);
        }
        __syncthreads();

        bf16x8 a0 = *(const bf16x8*)&As[(mw + r16) * AK + quad * 8];
        bf16x8 a1 = *(const bf16x8*)&As[(mw + 16 + r16) * AK + quad * 8];
#pragma unroll
        for (int nt = 0; nt < 4; nt++) {
            bf16x8 bfr = *(const bf16x8*)&Ws[(nt * 16 + r16) * AK + quad * 8];
            acc[0][nt] = __builtin_amdgcn_mfma_f32_16x16x32_bf16(a0, bfr, acc[0][nt], 0, 0, 0);
            acc[1][nt] = __builtin_amdgcn_mfma_f32_16x16x32_bf16(a1, bfr, acc[1][nt], 0, 0, 0);
        }
        __syncthreads();
    }

#pragma unroll
    for (int nt = 0; nt < 4; nt++) {
        int col = co0 + nt * 16 + r16;
        if (col >= 216) continue;
        float bias = (col < 144) ? b_off[col] : b_mask[col - 144];
#pragma unroll
        for (int mt = 0; mt < 2; mt++) {
            int mbase = m0 + mw + mt * 16 + quad * 4;
#pragma unroll
            for (int r = 0; r < 4; r++) {
                int p = mbase + r;
                float v = acc[mt][nt][r] + bias;
                if (col < 144) off[(size_t)p * 144 + col] = v;
                else           msk[(size_t)p * 72 + col - 144] = v;
            }
        }
    }
}

// ---------------------------------------------------------------------------
// Kernel 4: deformable sampling + aggregation, 4 pixels/block, bf16 xp/agg
// ---------------------------------------------------------------------------
__global__ __launch_bounds__(256) void k_sample_agg(
    const unsigned short* __restrict__ xp, const float* __restrict__ off,
    const float* __restrict__ msk, unsigned short* __restrict__ agg)
{
    __shared__ float  sm[288];
    __shared__ int2   tco[288];
    __shared__ float4 twt[288];

    const int tid = threadIdx.x;
    const int s0 = blockIdx.x * 4;

    if (tid < 32) {
        const int pix = tid >> 3, g = tid & 7;
        const float* mskp = msk + (size_t)(s0 + pix) * 72 + g * 9;
        float e[9];
        float mx = -1e30f;
#pragma unroll
        for (int p = 0; p < PP; p++) { e[p] = mskp[p]; mx = fmaxf(mx, e[p]); }
        float sum = 0.f;
#pragma unroll
        for (int p = 0; p < PP; p++) { e[p] = __expf(e[p] - mx); sum += e[p]; }
        float rs = 1.0f / sum;
#pragma unroll
        for (int p = 0; p < PP; p++) sm[tid * 9 + p] = e[p] * rs;
    }
    __syncthreads();

    for (int idx = tid; idx < 288; idx += 256) {
        int pix = idx / 72;
        int rem = idx - pix * 72;
        int g = rem / 9;
        int p = rem - g * 9;
        int s = s0 + pix;
        int hw = s & 4095;
        int h = hw >> 6, w = hw & 63;
        const float* offp = off + (size_t)s * 144 + g * 18 + p * 2;
        float ox = offp[0], oy = offp[1];
        int i = p / 3, j = p - i * 3;
        float fx = (float)(w + i) + ox;
        float fy = (float)(h + j) + oy;
        float x0f = floorf(fx), y0f = floorf(fy);
        int x0 = (int)x0f, y0 = (int)y0f;
        float wx = fx - x0f, wy = fy - y0f;
        float m = sm[idx];
        float w00 = (1.f - wx) * (1.f - wy) * m;
        float w10 = wx * (1.f - wy) * m;
        float w01 = (1.f - wx) * wy * m;
        float w11 = wx * wy * m;
        int x1c = x0 + 1, y1c = y0 + 1;
        if (!((x0  >= 0) && (x0  < WIN))) { w00 = 0.f; w01 = 0.f; }
        if (!((x1c >= 0) && (x1c < WIN))) { w10 = 0.f; w11 = 0.f; }
        if (!((y0  >= 0) && (y0  < HIN))) { w00 = 0.f; w10 = 0.f; }
        if (!((y1c >= 0) && (y1c < HIN))) { w01 = 0.f; w11 = 0.f; }
        int cx0 = min(max(x0, 0), WIN - 1), cx1 = min(max(x1c, 0), WIN - 1);
        int cy0 = min(max(y0, 0), HIN - 1), cy1 = min(max(y1c, 0), HIN - 1);
        tco[idx] = make_int2(cx0 | (cx1 << 16), cy0 | (cy1 << 16));
        twt[idx] = make_float4(w00, w10, w01, w11);
    }
    __syncthreads();

    const int pix = tid >> 6;
    const int lane = tid & 63;
    const int g = lane >> 3, c4 = lane & 7;
    const int s = s0 + pix;
    const int n = s >> 12;
    const unsigned short* base = xp + (size_t)n * HIN * WIN * CCH + g * GCH + c4 * 4;
    const int tbase = pix * 72 + g * 9;

    float ax = 0.f, ay = 0.f, az = 0.f, aw = 0.f;
#pragma unroll
    for (int p = 0; p < PP; p++) {
        int2 cc = tco[tbase + p];
        float4 wt = twt[tbase + p];
        int cx0 = cc.x & 0xFFFF, cx1 = cc.x >> 16;
        int cy0 = cc.y & 0xFFFF, cy1 = cc.y >> 16;
        const unsigned short* r0 = base + (size_t)(cy0 * WIN) * CCH;
        const unsigned short* r1 = base + (size_t)(cy1 * WIN) * CCH;
        ushort4 v00 = *(const ushort4*)&r0[(size_t)cx0 * CCH];
        ushort4 v10 = *(const ushort4*)&r0[(size_t)cx1 * CCH];
        ushort4 v01 = *(const ushort4*)&r1[(size_t)cx0 * CCH];
        ushort4 v11 = *(const ushort4*)&r1[(size_t)cx1 * CCH];
        ax += wt.x * bf2f(v00.x) + wt.y * bf2f(v10.x) + wt.z * bf2f(v01.x) + wt.w * bf2f(v11.x);
        ay += wt.x * bf2f(v00.y) + wt.y * bf2f(v10.y) + wt.z * bf2f(v01.y) + wt.w * bf2f(v11.y);
        az += wt.x * bf2f(v00.z) + wt.y * bf2f(v10.z) + wt.z * bf2f(v01.z) + wt.w * bf2f(v11.z);
        aw += wt.x * bf2f(v00.w) + wt.y * bf2f(v10.w) + wt.z * bf2f(v01.w) + wt.w * bf2f(v11.w);
    }

    ushort4 o; o.x = f2bf(ax); o.y = f2bf(ay); o.z = f2bf(az); o.w = f2bf(aw);
    *(ushort4*)&agg[(size_t)s * CCH + g * GCH + c4 * 4] = o;
}

// ---------------------------------------------------------------------------
// Kernel 5: agg(bf16) @ w_out + b_out -> BN -> SiLU -> out (NCHW fp32)
// ---------------------------------------------------------------------------
__global__ __launch_bounds__(256) void k_gemm_out(
    const unsigned short* __restrict__ agg, const float* __restrict__ w_out,
    const float* __restrict__ b_out, const float* __restrict__ bn_g,
    const float* __restrict__ bn_b, const float* __restrict__ bn_mean,
    const float* __restrict__ bn_var, float* __restrict__ out)
{
    __shared__ short As[128 * AK];
    __shared__ short Ws[64 * AK];

    const int m0  = blockIdx.x * 128;
    const int co0 = blockIdx.y * 64;
    const int tid = threadIdx.x;
    const int n   = m0 >> 12;
    const int hw0 = m0 & 4095;

    const int wave = tid >> 6;
    const int lane = tid & 63;
    const int r16  = lane & 15;
    const int quad = lane >> 4;
    const int mw   = wave * 32;

    f32x4 acc[2][4];
#pragma unroll
    for (int i = 0; i < 2; i++)
#pragma unroll
        for (int j = 0; j < 4; j++) acc[i][j] = (f32x4){0.f, 0.f, 0.f, 0.f};

    for (int k0 = 0; k0 < CCH; k0 += 32) {
#pragma unroll
        for (int l = 0; l < 2; l++) {
            int idx = tid + l * 256;
            int m = idx >> 2, kq = idx & 3;
            uint4 v = *(const uint4*)&agg[(size_t)(m0 + m) * CCH + k0 + kq * 8];
            *(uint4*)&As[m * AK + kq * 8] = v;
        }
#pragma unroll
        for (int l = 0; l < 4; l++) {
            int idx = tid + l * 256;
            int nn = idx & 63, kp = idx >> 6;
            float v0 = w_out[(size_t)(k0 + 2 * kp) * CCH + co0 + nn];
            float v1 = w_out[(size_t)(k0 + 2 * kp + 1) * CCH + co0 + nn];
            ((unsigned int*)Ws)[(nn * AK) / 2 + kp] = f2bf_pk(v0, v1);
        }
        __syncthreads();

        bf16x8 a0 = *(const bf16x8*)&As[(mw + r16) * AK + quad * 8];
        bf16x8 a1 = *(const bf16x8*)&As[(mw + 16 + r16) * AK + quad * 8];
#pragma unroll
        for (int nt = 0; nt < 4; nt++) {
            bf16x8 bfr = *(const bf16x8*)&Ws[(nt * 16 + r16) * AK + quad * 8];
            acc[0][nt] = __builtin_amdgcn_mfma_f32_16x16x32_bf16(a0, bfr, acc[0][nt], 0, 0, 0);
            acc[1][nt] = __builtin_amdgcn_mfma_f32_16x16x32_bf16(a1, bfr, acc[1][nt], 0, 0, 0);
        }
        __syncthreads();
    }

#pragma unroll
    for (int nt = 0; nt < 4; nt++) {
        int co = co0 + nt * 16 + r16;
        float mean = bn_mean[co];
        float rstd = rsqrtf(bn_var[co] + 1e-5f);
        float gg = bn_g[co], bb = bn_b[co], bo = b_out[co];
#pragma unroll
        for (int mt = 0; mt < 2; mt++) {
            int hwb = hw0 + mw + mt * 16 + quad * 4;
            float tmp[4];
#pragma unroll
            for (int r = 0; r < 4; r++) {
                float y = acc[mt][nt][r] + bo;
                float yh = (y - mean) * rstd * gg + bb;
                tmp[r] = yh / (1.0f + __expf(-yh));
            }
            float4 v = make_float4(tmp[0], tmp[1], tmp[2], tmp[3]);
            *(float4*)&out[((size_t)n * CCH + co) * HWSZ + hwb] = v;
        }
    }
}

// ---------------------------------------------------------------------------
extern "C" void kernel_launch(void* const* d_in, const int* in_sizes, int n_in,
                              void* d_out, int out_size, void* d_ws, size_t ws_size,
                              hipStream_t stream)
{
    const float* x       = (const float*)d_in[0];
    const float* w_in    = (const float*)d_in[1];
    const float* b_in    = (const float*)d_in[2];
    const float* w_dw    = (const float*)d_in[3];
    const float* b_dw    = (const float*)d_in[4];
    const float* ln_g    = (const float*)d_in[5];
    const float* ln_b    = (const float*)d_in[6];
    const float* w_off   = (const float*)d_in[7];
    const float* b_off   = (const float*)d_in[8];
    const float* w_mask  = (const float*)d_in[9];
    const float* b_mask  = (const float*)d_in[10];
    const float* w_out   = (const float*)d_in[11];
    const float* b_out   = (const float*)d_in[12];
    const float* bn_g    = (const float*)d_in[13];
    const float* bn_b    = (const float*)d_in[14];
    const float* bn_mean = (const float*)d_in[15];
    const float* bn_var  = (const float*)d_in[16];
    float* out = (float*)d_out;

    // Workspace: bf16 buffers first (ushort), then fp32 buffers
    unsigned short* xp  = (unsigned short*)d_ws;
    unsigned short* x1  = xp + XP_ELEMS;
    unsigned short* agg = x1 + X1_ELEMS;
    float* off = (float*)(agg + AGG_ELEMS);
    float* msk = off + OFF_ELEMS;
    // total: (4460544+4194304+4194304)*2 + (2359296+1179648)*4 = ~39.8 MB

    k_zero_ring<<<dim3(1040), 64, 0, stream>>>(xp);
    k_gemm_in<<<dim3(128, 4), 256, 0, stream>>>(x, w_in, b_in, xp);
    k_dw_ln_gelu<<<dim3(64, 4), 512, 0, stream>>>(x, w_dw, b_dw, ln_g, ln_b, x1);
    k_gemm_offmask<<<dim3(128, 4), 256, 0, stream>>>(x1, w_off, b_off, w_mask, b_mask, off, msk);
    k_sample_agg<<<dim3(4096), 256, 0, stream>>>(xp, off, msk, agg);
    k_gemm_out<<<dim3(128, 4), 256, 0, stream>>>(agg, w_out, b_out, bn_g, bn_b, bn_mean, bn_var, out);
}